// Round 2
// baseline (44354.480 us; speedup 1.0000x reference)
//
#include <hip/hip_runtime.h>
#include <cstdint>

#define VOCAB 50257
#define EXTRA 64
#define VTOT  50321
#define SEQ   1024
#define TDEC  100
#define UNK   3
#define VPB   197          // vocab entries per block in final stage (197*256=50432>=50321)

// ---------------- workspace layout (float offsets) ----------------
static const size_t OFF_EMB    = 0;        // [1024][128]
static const size_t OFF_WIHT_F = 131072;   // [128][640]
static const size_t OFF_WIHT_B = 212992;   // [128][640]
static const size_t OFF_WTE    = 294912;   // [320][320]  enc_attn_proj^T
static const size_t OFF_XG     = 397312;   // [2][1024][640]
static const size_t OFF_ENCH   = 1708032;  // [1024][320]
static const size_t OFF_EPH    = 2035712;  // [1024][320]
static const size_t OFF_DECBUF = 2363392;  // [100][320]
static const size_t OFF_LOGITS = 2395392;  // 50272
static const size_t OFF_SCORES = 2445664;  // 1024
static const size_t OFF_HP     = 2446688;  // 320
static const size_t OFF_CENC   = 2447008;  // 320 (global enc_ctx accumulator)
static const size_t OFF_GATES  = 2447328;  // 1280
static const size_t OFF_BM     = 2448608;  // 256
static const size_t OFF_BS     = 2448864;  // 256
static const size_t OFF_AVAL   = 2449120;  // 256
static const size_t OFF_AIDX   = 2449376;  // 256 (int)
static const size_t OFF_H0     = 2449632;  // 320
static const size_t OFF_SCAL   = 2449952;  // [0]=p_copy
static const size_t OFF_BAR    = 2449956;  // barrier counter (u32)
static const size_t OFF_SKEY   = 2449984;  // 1024 (int) sorted id values
static const size_t OFF_SPOS   = 2451008;  // 1024 (int) sorted source positions
static const size_t OFF_BSTART = 2452032;  // 257 (int)
static const size_t OFF_WBF16  = 2452352;  // bf16 out_proj, 50257*480 u32

__device__ __forceinline__ float sigmf(float x) { return 1.f / (1.f + expf(-x)); }

__device__ __forceinline__ float wsum64(float x) {
#pragma unroll
  for (int m = 1; m < 64; m <<= 1) x += __shfl_xor(x, m, 64);
  return x;
}

__device__ __forceinline__ unsigned short bf16r(float x) {
  uint32_t b = __float_as_uint(x);
  uint32_t r = (b + 0x7fffu + ((b >> 16) & 1u)) >> 16;
  return (unsigned short)r;
}

// grid barrier: monotonic counter zeroed by k_setup each call
__device__ __forceinline__ void gbar(unsigned* bar, unsigned target) {
  __threadfence();
  __syncthreads();
  if (threadIdx.x == 0) {
    atomicAdd(bar, 1u);
    while (__hip_atomic_load(bar, __ATOMIC_RELAXED, __HIP_MEMORY_SCOPE_AGENT) < target)
      __builtin_amdgcn_s_sleep(1);
    __threadfence();
  }
  __syncthreads();
}

// ---------------- setup: embedding gather, weight transposes, barrier reset ----------------
__global__ __launch_bounds__(256) void k_setup(float* __restrict__ ws, const int* __restrict__ ids,
                                               const float* __restrict__ embt, const float* __restrict__ ewf,
                                               const float* __restrict__ ewb, const float* __restrict__ eap) {
  int idx = blockIdx.x * 256 + threadIdx.x;
  if (idx == 0) *(unsigned*)(ws + OFF_BAR) = 0u;
  if (idx < 131072) {
    int tt = idx >> 7, e = idx & 127;
    int id = ids[tt]; if (id >= VOCAB) id = UNK;
    ws[OFF_EMB + idx] = embt[(size_t)id * 128 + e];
  } else if (idx < 212992) {
    int i = idx - 131072;
    int k = i / 640, g = i - (i / 640) * 640;
    ws[OFF_WIHT_F + i] = ewf[(size_t)g * 128 + k];
  } else if (idx < 294912) {
    int i = idx - 212992;
    int k = i / 640, g = i - (i / 640) * 640;
    ws[OFF_WIHT_B + i] = ewb[(size_t)g * 128 + k];
  } else if (idx < 397312) {
    int i = idx - 294912;
    int k = i / 320, j = i - (i / 320) * 320;
    ws[OFF_WTE + i] = eap[(size_t)j * 320 + k];
  }
}

// ---------------- the fused persistent kernel ----------------
__global__ __launch_bounds__(512, 2) void k_fused(
    float* __restrict__ ws, float* __restrict__ out, const int* __restrict__ ids,
    const float* __restrict__ embt,
    const float* __restrict__ dwih, const float* __restrict__ dwhh,
    const float* __restrict__ dbih, const float* __restrict__ dbhh,
    const float* __restrict__ dap, const float* __restrict__ ob,
    const float* __restrict__ sw, const float* __restrict__ sb,
    const float* __restrict__ ebif, const float* __restrict__ ebhf,
    const float* __restrict__ ebib, const float* __restrict__ ebhb,
    const float* __restrict__ whh_f, const float* __restrict__ whh_b,
    const float* __restrict__ vp) {
  __shared__ float POOL[16000];  // 62.5 KB, multi-purpose
  float* cumL    = POOL;          // 1024
  float* attnL   = POOL + 1024;   // 1024
  float* concatL = POOL + 2048;   // 960  [h | enc_ctx | dec_ctx]
  float* cL      = POOL + 3008;   // 320
  float* redA    = POOL + 3328;   // 512
  int*   redI    = (int*)(POOL + 3840); // 512
  float* redB    = POOL + 4352;   // 512
  float* dsL     = POOL + 4864;   // 128
  float* daL     = POOL + 4992;   // 128

  const int tid = threadIdx.x, bid = blockIdx.x;
  unsigned* bar = (unsigned*)(ws + OFF_BAR);
  unsigned bt = 0;

  // ======== Stage A: encoder x-part gates ========
  {
    const int base = bid * 512 + tid;
#pragma unroll
    for (int i = 0; i < 10; ++i) {
      int idx = i * 131072 + base;
      int d = idx / 655360;
      int r = idx - d * 655360;
      int tt = r / 640, g = r - (r / 640) * 640;
      const float* wT = ws + (d ? OFF_WIHT_B : OFF_WIHT_F);
      const float* er = ws + OFF_EMB + (size_t)(d ? (1023 - tt) : tt) * 128;
      float acc = d ? (ebib[g] + ebhb[g]) : (ebif[g] + ebhf[g]);
#pragma unroll 4
      for (int k = 0; k < 128; ++k) acc += er[k] * wT[(size_t)k * 640 + g];
      ws[OFF_XG + idx] = acc;
    }
  }
  bt += 256; gbar(bar, bt);

  // ======== Stage B: encoder (blocks 0,1) || out_proj GEMM (blocks 2..255) ========
  if (bid < 2) {
    const int dir = bid;
    const float* whh = dir ? whh_b : whh_f;
    const float* xg = ws + OFF_XG + (size_t)dir * 655360;
    float* hbuf = POOL;        // 160
    float* part = POOL + 160;  // [4][640]
    const int q = tid & 127, kg = tid >> 7, ks = kg * 40;
    float w[5][40];
#pragma unroll
    for (int j = 0; j < 5; ++j)
#pragma unroll
      for (int i = 0; i < 40; ++i)
        w[j][i] = whh[(size_t)(5 * q + j) * 160 + ks + i];
    float cst = 0.f;
    if (tid < 160) hbuf[tid] = 0.f;
    __syncthreads();
    for (int t = 0; t < 1024; ++t) {
      float acc[5] = {0.f, 0.f, 0.f, 0.f, 0.f};
#pragma unroll
      for (int i4 = 0; i4 < 10; ++i4) {
        float4 h4 = *(const float4*)&hbuf[ks + i4 * 4];
#pragma unroll
        for (int j = 0; j < 5; ++j)
          acc[j] += w[j][i4 * 4 + 0] * h4.x + w[j][i4 * 4 + 1] * h4.y + w[j][i4 * 4 + 2] * h4.z + w[j][i4 * 4 + 3] * h4.w;
      }
#pragma unroll
      for (int j = 0; j < 5; ++j) part[kg * 640 + 5 * q + j] = acc[j];
      __syncthreads();
      if (tid < 160) {
        float gi = xg[(size_t)t * 640 + tid];
        float gf = xg[(size_t)t * 640 + 160 + tid];
        float gg = xg[(size_t)t * 640 + 320 + tid];
        float go = xg[(size_t)t * 640 + 480 + tid];
#pragma unroll
        for (int k2 = 0; k2 < 4; ++k2) {
          gi += part[k2 * 640 + tid]; gf += part[k2 * 640 + 160 + tid];
          gg += part[k2 * 640 + 320 + tid]; go += part[k2 * 640 + 480 + tid];
        }
        cst = sigmf(gf) * cst + sigmf(gi) * tanhf(gg);
        float hn = sigmf(go) * tanhf(cst);
        hbuf[tid] = hn;
        int trow = dir ? (1023 - t) : t;
        ws[OFF_ENCH + (size_t)trow * 320 + dir * 160 + tid] = hn;
      }
      __syncthreads();
    }
    if (tid < 160) ws[OFF_H0 + dir * 160 + tid] = hbuf[tid];
  } else {
    float* As = POOL;         // [64][129]
    float* Bs = POOL + 8256;  // [64][64]
    unsigned short* W = (unsigned short*)(ws + OFF_WBF16);
    const int mi = tid >> 4, ni = tid & 15;
    for (int tile = bid - 2; tile < 786 * 15; tile += 254) {
      int v0 = (tile % 786) * 64, n0 = (tile / 786) * 64;
      __syncthreads();
#pragma unroll
      for (int c = 0; c < 16; ++c) {
        int idx = c * 512 + tid;
        int m = idx >> 7, k = idx & 127;
        As[m * 129 + k] = (v0 + m < VOCAB) ? embt[(size_t)(v0 + m) * 128 + k] : 0.f;
      }
      float acc[2][4] = {};
      for (int half = 0; half < 2; ++half) {
        __syncthreads();
#pragma unroll
        for (int c = 0; c < 8; ++c) {
          int idx = c * 512 + tid;
          int k = idx >> 6, n = idx & 63;
          Bs[k * 64 + n] = vp[(size_t)(half * 64 + k) * 960 + n0 + n];
        }
        __syncthreads();
        for (int k = 0; k < 64; ++k) {
          float a0 = As[(mi * 2) * 129 + half * 64 + k];
          float a1 = As[(mi * 2 + 1) * 129 + half * 64 + k];
          float4 b = *(const float4*)&Bs[k * 64 + ni * 4];
          acc[0][0] += a0 * b.x; acc[0][1] += a0 * b.y; acc[0][2] += a0 * b.z; acc[0][3] += a0 * b.w;
          acc[1][0] += a1 * b.x; acc[1][1] += a1 * b.y; acc[1][2] += a1 * b.z; acc[1][3] += a1 * b.w;
        }
      }
#pragma unroll
      for (int i = 0; i < 2; ++i) {
        int v = v0 + mi * 2 + i;
        if (v < VOCAB) {
          ushort4 pk;
          pk.x = bf16r(tanhf(acc[i][0])); pk.y = bf16r(tanhf(acc[i][1]));
          pk.z = bf16r(tanhf(acc[i][2])); pk.w = bf16r(tanhf(acc[i][3]));
          *(ushort4*)&W[(size_t)v * 960 + n0 + ni * 4] = pk;
        }
      }
    }
  }
  bt += 256; gbar(bar, bt);

  // ======== Stage C: enc_proj_h + per-block decoder init + id sort (block 0) ========
  if (tid < 320) {
    for (int r = 0; r < 4; ++r) {
      int s = bid * 4 + r;
      const float* er = ws + OFF_ENCH + (size_t)s * 320;
      const float* wt = ws + OFF_WTE;
      float acc = 0.f;
#pragma unroll 4
      for (int k = 0; k < 320; ++k) acc += er[k] * wt[(size_t)k * 320 + tid];
      ws[OFF_EPH + (size_t)s * 320 + tid] = acc;
    }
    cL[tid] = 0.f;
    concatL[tid] = ws[OFF_H0 + tid];
  }
  cumL[tid] = 0.f; cumL[512 + tid] = 0.f;
  __syncthreads();
  if (bid == 0) {
    int* sk = (int*)(POOL + 8000);
    int* sp = (int*)(POOL + 9024);
    for (int j = tid; j < 1024; j += 512) { sk[j] = ids[j]; sp[j] = j; }
    __syncthreads();
    for (int k = 2; k <= 1024; k <<= 1)
      for (int j = k >> 1; j > 0; j >>= 1) {
        for (int i = tid; i < 1024; i += 512) {
          int ixj = i ^ j;
          if (ixj > i) {
            bool up = ((i & k) == 0);
            int a = sk[i], b2 = sk[ixj];
            if (up ? (a > b2) : (a < b2)) {
              sk[i] = b2; sk[ixj] = a;
              int pa = sp[i]; sp[i] = sp[ixj]; sp[ixj] = pa;
            }
          }
        }
        __syncthreads();
      }
    int* BST = (int*)(ws + OFF_BSTART);
    int* SK = (int*)(ws + OFF_SKEY);
    int* SP = (int*)(ws + OFF_SPOS);
    for (int j = tid; j < 1024; j += 512) {
      SK[j] = sk[j]; SP[j] = sp[j];
      int o1 = sk[j] / VPB;
      int o0 = (j == 0) ? -1 : (sk[j - 1] / VPB);
      for (int o = o0 + 1; o <= o1; ++o) BST[o] = j;
    }
    if (tid == 0) {
      int olast = sk[1023] / VPB;
      for (int o = olast + 1; o <= 256; ++o) BST[o] = 1024;
    }
  }
  bt += 256; gbar(bar, bt);

  // ======== decode loop ========
  const uint32_t* W = (const uint32_t*)(ws + OFF_WBF16);
  const int* BST = (const int*)(ws + OFF_BSTART);
  const int* SK = (const int*)(ws + OFF_SKEY);
  const int* SP = (const int*)(ws + OFF_SPOS);
  int* AIX = (int*)(ws + OFF_AIDX);
  const int l = tid & 63, wv = tid >> 6;
  int token = 0;

  for (int t = 0; t < TDEC; ++t) {
    // ---- S0: token reduce (t>0) + gates ----
    if (t > 0) {
      if (tid < 256) { redA[tid] = ws[OFF_AVAL + tid]; redI[tid] = AIX[tid]; }
      __syncthreads();
      for (int off = 128; off > 0; off >>= 1) {
        if (tid < off) {
          float v2 = redA[tid + off]; int i2 = redI[tid + off];
          if (v2 > redA[tid] || (v2 == redA[tid] && i2 < redI[tid])) { redA[tid] = v2; redI[tid] = i2; }
        }
        __syncthreads();
      }
      token = redI[0];
      __syncthreads();
    }
    int tokm = (token >= VOCAB) ? UNK : token;
    {
      int g = bid * 8 + wv;
      if (g < 1280) {
        float xv0 = embt[(size_t)tokm * 128 + l];
        float xv1 = embt[(size_t)tokm * 128 + 64 + l];
        float hv[5];
#pragma unroll
        for (int c = 0; c < 5; ++c) hv[c] = concatL[c * 64 + l];
        float acc = dwih[(size_t)g * 128 + l] * xv0 + dwih[(size_t)g * 128 + 64 + l] * xv1;
#pragma unroll
        for (int c = 0; c < 5; ++c) acc += dwhh[(size_t)g * 320 + c * 64 + l] * hv[c];
        acc = wsum64(acc);
        if (l == 0) ws[OFF_GATES + g] = acc + dbih[g] + dbhh[g];
      }
      if (bid == 200 && tid < 320) ws[OFF_HP + tid] = 0.f;
      if (bid == 201 && tid < 320) ws[OFF_CENC + tid] = 0.f;
    }
    bt += 256; gbar(bar, bt);

    // ---- S1: h,c update (redundant) + scores + hp partials + decbuf ----
    if (tid < 320) {
      float gi = ws[OFF_GATES + tid];
      float gf = ws[OFF_GATES + 320 + tid];
      float gg = ws[OFF_GATES + 640 + tid];
      float go = ws[OFF_GATES + 960 + tid];
      float c = sigmf(gf) * cL[tid] + sigmf(gi) * tanhf(gg);
      cL[tid] = c;
      concatL[tid] = sigmf(go) * tanhf(c);
    }
    __syncthreads();
    {
      int g = bid * 8 + wv;
      if (g < 1024) {
        const float* er = ws + OFF_EPH + (size_t)g * 320;
        float acc = 0.f;
#pragma unroll
        for (int c = 0; c < 5; ++c) acc += er[c * 64 + l] * concatL[c * 64 + l];
        acc = wsum64(acc);
        if (l == 0) ws[OFF_SCORES + g] = acc;
      }
      if (bid >= 128 && bid < 136 && tid < 320) {
        int q = bid - 128;
        float acc = 0.f;
#pragma unroll 8
        for (int ii = 0; ii < 40; ++ii) {
          int i = q * 40 + ii;
          acc += concatL[i] * dap[(size_t)i * 320 + tid];
        }
        atomicAdd(&ws[OFF_HP + tid], acc);
      }
      if (bid == 136 && tid < 320) ws[OFF_DECBUF + (size_t)t * 320 + tid] = concatL[tid];
    }
    bt += 256; gbar(bar, bt);

    // ---- S2: temporal softmax (redundant) + enc_ctx partials + dec attention (redundant) ----
    {
      float s0 = ws[OFF_SCORES + tid], s1 = ws[OFF_SCORES + 512 + tid];
      float t0 = (t == 0) ? s0 : expf(s0) / cumL[tid];
      float t1 = (t == 0) ? s1 : expf(s1) / cumL[512 + tid];
      cumL[tid] += s0; cumL[512 + tid] += s1;
      redA[tid] = fmaxf(t0, t1);
      __syncthreads();
      for (int off = 256; off > 0; off >>= 1) { if (tid < off) redA[tid] = fmaxf(redA[tid], redA[tid + off]); __syncthreads(); }
      float mx = redA[0];
      __syncthreads();
      redA[tid] = expf(t0 - mx) + expf(t1 - mx);
      __syncthreads();
      for (int off = 256; off > 0; off >>= 1) { if (tid < off) redA[tid] += redA[tid + off]; __syncthreads(); }
      float Ssm = redA[0];
      __syncthreads();
      attnL[tid] = expf(t0 - mx) / Ssm;
      attnL[512 + tid] = expf(t1 - mx) / Ssm;
      // dec scores
      float hpv[5];
#pragma unroll
      for (int c = 0; c < 5; ++c) hpv[c] = ws[OFF_HP + c * 64 + l];
      if (tid < 28) dsL[100 + tid] = -1e30f;
#pragma unroll
      for (int k2 = 0; k2 < 13; ++k2) {
        int tp = wv + 8 * k2;
        if (tp < 100) {
          float acc = 0.f;
#pragma unroll
          for (int c = 0; c < 5; ++c) acc += hpv[c] * ws[OFF_DECBUF + (size_t)tp * 320 + c * 64 + l];
          acc = wsum64(acc);
          if (l == 0) dsL[tp] = acc;
        }
      }
      __syncthreads();  // attnL + dsL ready
      if (bid < 32 && tid < 320) {
        float acc = 0.f;
        const float* eh = ws + OFF_ENCH + (size_t)(bid * 32) * 320 + tid;
#pragma unroll 4
        for (int k2 = 0; k2 < 32; ++k2) acc += attnL[bid * 32 + k2] * eh[(size_t)k2 * 320];
        atomicAdd(&ws[OFF_CENC + tid], acc);
      }
      float dv = -1e30f;
      if (tid < 128) { dv = (tid < t) ? dsL[tid] : -1e30f; redA[tid] = dv; }
      __syncthreads();
      for (int off = 64; off > 0; off >>= 1) { if (tid < off) redA[tid] = fmaxf(redA[tid], redA[tid + off]); __syncthreads(); }
      float dmx = redA[0];
      __syncthreads();
      float de = (tid < 128) ? expf(dv - dmx) : 0.f;
      if (tid < 128) redA[tid] = de;
      __syncthreads();
      for (int off = 64; off > 0; off >>= 1) { if (tid < off) redA[tid] += redA[tid + off]; __syncthreads(); }
      float dS = redA[0];
      __syncthreads();
      if (tid < 128) daL[tid] = de / dS;
      __syncthreads();
      if (tid < 320) {
        float acc = 0.f;
        for (int tp = 0; tp < t; ++tp) acc += daL[tp] * ws[OFF_DECBUF + (size_t)tp * 320 + tid];
        concatL[640 + tid] = acc;
      }
    }
    bt += 256; gbar(bar, bt);

    // ---- S3: assemble concat, p_copy, logits + per-block online softmax ----
    if (tid < 320) concatL[320 + tid] = ws[OFF_CENC + tid];
    __syncthreads();
    if (bid == 0 && tid < 64) {
      float acc = 0.f;
#pragma unroll
      for (int c = 0; c < 15; ++c) acc += sw[c * 64 + l] * concatL[c * 64 + l];
      acc = wsum64(acc);
      if (l == 0) ws[OFF_SCAL] = 1.f / (1.f + expf(-(acc + sb[0])));
    }
    {
      const float2* cL2 = (const float2*)concatL;
      float cc0[7], cc1[7], ct0 = 0.f, ct1 = 0.f;
#pragma unroll
      for (int c = 0; c < 7; ++c) { float2 x = cL2[c * 64 + l]; cc0[c] = x.x; cc1[c] = x.y; }
      if (l < 32) { ct0 = concatL[896 + 2 * l]; ct1 = concatL[897 + 2 * l]; }
      float m = -1e30f, ssum = 0.f;
      int g = bid * 8 + wv;
      for (int v = g; v < VOCAB; v += 2048) {
        const uint32_t* row = W + (size_t)v * 480;
        float acc = 0.f;
#pragma unroll
        for (int c = 0; c < 7; ++c) {
          uint32_t u = row[c * 64 + l];
          acc += __uint_as_float(u << 16) * cc0[c] + __uint_as_float(u & 0xffff0000u) * cc1[c];
        }
        if (l < 32) {
          uint32_t u = row[448 + l];
          acc += __uint_as_float(u << 16) * ct0 + __uint_as_float(u & 0xffff0000u) * ct1;
        }
        acc = wsum64(acc);
        if (l == 0) {
          float logit = acc + ob[v];
          ws[OFF_LOGITS + v] = logit;
          float m2 = fmaxf(m, logit);
          ssum = ssum * expf(m - m2) + expf(logit - m2);
          m = m2;
        }
      }
      redA[tid] = m; redB[tid] = ssum;
      __syncthreads();
      for (int off = 256; off > 0; off >>= 1) {
        if (tid < off) {
          float m1 = redA[tid], m2 = redA[tid + off];
          float mm = fmaxf(m1, m2);
          redB[tid] = redB[tid] * expf(m1 - mm) + redB[tid + off] * expf(m2 - mm);
          redA[tid] = mm;
        }
        __syncthreads();
      }
      if (tid == 0) { ws[OFF_BM + bid] = redA[0]; ws[OFF_BS + bid] = redB[0]; }
    }
    bt += 256; gbar(bar, bt);

    // ---- S4: global softmax reduce (redundant), final write + scatter + argmax partial ----
    {
      if (tid < 256) { redA[tid] = ws[OFF_BM + tid]; redB[tid] = ws[OFF_BS + tid]; }
      __syncthreads();
      for (int off = 128; off > 0; off >>= 1) {
        if (tid < off) {
          float m1 = redA[tid], m2 = redA[tid + off];
          float mm = fmaxf(m1, m2);
          redB[tid] = redB[tid] * expf(m1 - mm) + redB[tid + off] * expf(m2 - mm);
          redA[tid] = mm;
        }
        __syncthreads();
      }
      float M = redA[0], Ssum = redB[0];
      float pc = ws[OFF_SCAL];
      float scale = (1.f - pc) / Ssum;
      int v = bid * VPB + tid;
      bool act = (tid < VPB) && (v < VTOT);
      float val = -1e30f;
      if (act) {
        val = (v < VOCAB) ? scale * expf(ws[OFF_LOGITS + v] - M) : 0.f;
        int jb = BST[bid], je = BST[bid + 1];
        for (int j = jb; j < je; ++j)
          if (SK[j] == v) val += pc * attnL[SP[j]];
        out[(size_t)t * VTOT + v] = val;
      }
      __syncthreads();
      redA[tid] = act ? val : -1e30f; redI[tid] = v;
      __syncthreads();
      for (int off = 256; off > 0; off >>= 1) {
        if (tid < off) {
          float v2 = redA[tid + off]; int i2 = redI[tid + off];
          if (v2 > redA[tid] || (v2 == redA[tid] && i2 < redI[tid])) { redA[tid] = v2; redI[tid] = i2; }
        }
        __syncthreads();
      }
      if (tid == 0) { ws[OFF_AVAL + bid] = redA[0]; AIX[bid] = redI[0]; }
    }
    bt += 256; gbar(bar, bt);
  }
}

// ---------------- host ----------------
extern "C" void kernel_launch(void* const* d_in, const int* in_sizes, int n_in,
                              void* d_out, int out_size, void* d_ws, size_t ws_size,
                              hipStream_t stream) {
  const int*   ids  = (const int*)d_in[0];
  const float* embt = (const float*)d_in[1];
  const float* ewf  = (const float*)d_in[2];
  const float* ehf  = (const float*)d_in[3];
  const float* ebif = (const float*)d_in[4];
  const float* ebhf = (const float*)d_in[5];
  const float* ewb  = (const float*)d_in[6];
  const float* ehb  = (const float*)d_in[7];
  const float* ebib = (const float*)d_in[8];
  const float* ebhb = (const float*)d_in[9];
  const float* dwih = (const float*)d_in[10];
  const float* dwhh = (const float*)d_in[11];
  const float* dbih = (const float*)d_in[12];
  const float* dbhh = (const float*)d_in[13];
  const float* eap  = (const float*)d_in[14];
  const float* dap  = (const float*)d_in[15];
  const float* vp   = (const float*)d_in[16];
  const float* ob   = (const float*)d_in[17];
  const float* sw   = (const float*)d_in[18];
  const float* sb   = (const float*)d_in[19];
  float* out = (float*)d_out;
  float* ws  = (float*)d_ws;

  k_setup<<<1552, 256, 0, stream>>>(ws, ids, embt, ewf, ewb, eap);
  k_fused<<<256, 512, 0, stream>>>(ws, out, ids, embt, dwih, dwhh, dbih, dbhh,
                                   dap, ob, sw, sb, ebif, ebhf, ebib, ebhb,
                                   ehf, ehb, vp);
}

// Round 3
// 23462.321 us; speedup vs baseline: 1.8905x; 1.8905x over previous
//
#include <hip/hip_runtime.h>
#include <cstdint>

#define VOCAB 50257
#define VTOT  50321
#define TDEC  100
#define UNK   3
#define VPB   197          // vocab slice per block (197*256=50432 >= 50321)

// ---------------- workspace layout (float offsets) ----------------
static const size_t OFF_EMB    = 0;        // [1024][128]
static const size_t OFF_WIHT_F = 131072;   // [128][640]
static const size_t OFF_WIHT_B = 212992;   // [128][640]
static const size_t OFF_WTE    = 294912;   // [320][320]  enc_attn_proj^T
static const size_t OFF_XG     = 397312;   // [2][1024][640]
static const size_t OFF_ENCH   = 1708032;  // [1024][320]
static const size_t OFF_EPH    = 2035712;  // [1024][320]
static const size_t OFF_SCORES = 2445664;  // 1024
static const size_t OFF_HP     = 2446688;  // 320
static const size_t OFF_CENC   = 2447008;  // 320
static const size_t OFF_GATES  = 2447328;  // 1280
static const size_t OFF_BM     = 2448608;  // 256
static const size_t OFF_BS     = 2448864;  // 256
static const size_t OFF_AVAL   = 2449120;  // 256
static const size_t OFF_AIDX   = 2449376;  // 256 (int)
static const size_t OFF_H0     = 2449632;  // 320
static const size_t OFF_BAR    = 2449956;  // barrier counter (u32)
static const size_t OFF_SKEY   = 2449984;  // 1024 (int)
static const size_t OFF_SPOS   = 2451008;  // 1024 (int)
static const size_t OFF_BSTART = 2452032;  // 257 (int)
static const size_t OFF_WBF16  = 2452352;  // bf16 out_proj, 50257*480 u32

__device__ __forceinline__ float sigmf(float x) { return 1.f / (1.f + expf(-x)); }

__device__ __forceinline__ float wsum64(float x) {
#pragma unroll
  for (int m = 1; m < 64; m <<= 1) x += __shfl_xor(x, m, 64);
  return x;
}

__device__ __forceinline__ unsigned short bf16r(float x) {
  uint32_t b = __float_as_uint(x);
  uint32_t r = (b + 0x7fffu + ((b >> 16) & 1u)) >> 16;
  return (unsigned short)r;
}

// agent-scope, L2-bypassing (sc1) accesses: coherent across XCDs, no fence needed
__device__ __forceinline__ float scld(const float* p) {
  return __hip_atomic_load(p, __ATOMIC_RELAXED, __HIP_MEMORY_SCOPE_AGENT);
}
__device__ __forceinline__ int scldi(const int* p) {
  return __hip_atomic_load(p, __ATOMIC_RELAXED, __HIP_MEMORY_SCOPE_AGENT);
}
__device__ __forceinline__ void scst(float* p, float v) {
  __hip_atomic_store(p, v, __ATOMIC_RELAXED, __HIP_MEMORY_SCOPE_AGENT);
}
__device__ __forceinline__ void scsti(int* p, int v) {
  __hip_atomic_store(p, v, __ATOMIC_RELAXED, __HIP_MEMORY_SCOPE_AGENT);
}

__device__ __forceinline__ float fp8dec(unsigned w, int sel) {
  return __builtin_amdgcn_cvt_f32_fp8((int)((w >> (sel * 8)) & 0xffu), 0);
}

// lightweight barrier: NO threadfence (no L2 writeback/invalidate). Safe because
// all cross-block decode data goes through agent-scope (sc) accesses.
__device__ __forceinline__ void gbar_lite(unsigned* bar, unsigned target) {
  __syncthreads();  // drains vmcnt: prior sc stores are at the coherence point
  if (threadIdx.x == 0) {
    __hip_atomic_fetch_add(bar, 1u, __ATOMIC_RELAXED, __HIP_MEMORY_SCOPE_AGENT);
    while (__hip_atomic_load(bar, __ATOMIC_RELAXED, __HIP_MEMORY_SCOPE_AGENT) < target)
      __builtin_amdgcn_s_sleep(8);
  }
  __syncthreads();
}

// full barrier for prologue stage boundaries (cached-data handoff)
__device__ __forceinline__ void gbar_full(unsigned* bar, unsigned target) {
  __threadfence();
  __syncthreads();
  if (threadIdx.x == 0) {
    __hip_atomic_fetch_add(bar, 1u, __ATOMIC_RELAXED, __HIP_MEMORY_SCOPE_AGENT);
    while (__hip_atomic_load(bar, __ATOMIC_RELAXED, __HIP_MEMORY_SCOPE_AGENT) < target)
      __builtin_amdgcn_s_sleep(8);
    __threadfence();
  }
  __syncthreads();
}

// ---------------- setup: embedding gather, weight transposes, barrier reset ----------------
__global__ __launch_bounds__(256) void k_setup(float* __restrict__ ws, const int* __restrict__ ids,
                                               const float* __restrict__ embt, const float* __restrict__ ewf,
                                               const float* __restrict__ ewb, const float* __restrict__ eap) {
  int idx = blockIdx.x * 256 + threadIdx.x;
  if (idx == 0) *(unsigned*)(ws + OFF_BAR) = 0u;
  if (idx < 131072) {
    int tt = idx >> 7, e = idx & 127;
    int id = ids[tt]; if (id >= VOCAB) id = UNK;
    ws[OFF_EMB + idx] = embt[(size_t)id * 128 + e];
  } else if (idx < 212992) {
    int i = idx - 131072;
    int k = i / 640, g = i - (i / 640) * 640;
    ws[OFF_WIHT_F + i] = ewf[(size_t)g * 128 + k];
  } else if (idx < 294912) {
    int i = idx - 212992;
    int k = i / 640, g = i - (i / 640) * 640;
    ws[OFF_WIHT_B + i] = ewb[(size_t)g * 128 + k];
  } else if (idx < 397312) {
    int i = idx - 294912;
    int k = i / 320, j = i - (i / 320) * 320;
    ws[OFF_WTE + i] = eap[(size_t)j * 320 + k];
  }
}

// ---------------- fused persistent kernel ----------------
__global__ __launch_bounds__(512, 2) void k_fused(
    float* __restrict__ ws, float* __restrict__ out, const int* __restrict__ ids,
    const float* __restrict__ embt,
    const float* __restrict__ dwih, const float* __restrict__ dwhh,
    const float* __restrict__ dbih, const float* __restrict__ dbhh,
    const float* __restrict__ dap, const float* __restrict__ ob,
    const float* __restrict__ sw, const float* __restrict__ sb,
    const float* __restrict__ ebif, const float* __restrict__ ebhf,
    const float* __restrict__ ebib, const float* __restrict__ ebhb,
    const float* __restrict__ whh_f, const float* __restrict__ whh_b,
    const float* __restrict__ vp) {
  __shared__ float POOL[12352];  // 49.4 KB
  // decode-phase layout
  unsigned* decbufU = (unsigned*)POOL;       // [100][80] u32 = fp8 x4 (32 KB)
  float* attnL   = POOL + 8000;   // 1024
  float* concatL = POOL + 9024;   // 960  [h | enc_ctx | dec_ctx]
  float* redA    = POOL + 9984;   // 512
  float* redB    = POOL + 10496;  // 512
  int*   redI    = (int*)(POOL + 11008); // 512
  float* dsL     = POOL + 11520;  // 128
  float* daL     = POOL + 11648;  // 128
  float* logitsL = POOL + 11776;  // 200
  float* hpL     = POOL + 11976;  // 320
  float* scalL   = POOL + 12296;  // 1
  // prologue aliases
  float* As   = POOL;             // 64x129
  float* Bs   = POOL + 8256;      // 64x64
  float* hbuf = POOL;             // 160
  float* part = POOL + 160;       // 4x640

  const int tid = threadIdx.x, bid = blockIdx.x;
  const int l = tid & 63, wv = tid >> 6;
  unsigned* bar = (unsigned*)(ws + OFF_BAR);
  unsigned bt = 0;

  // ======== Stage A: encoder x-part gates ========
  {
    const int base = bid * 512 + tid;
#pragma unroll
    for (int i = 0; i < 10; ++i) {
      int idx = i * 131072 + base;
      int d = idx / 655360;
      int r = idx - d * 655360;
      int tt = r / 640, g = r - (r / 640) * 640;
      const float* wT = ws + (d ? OFF_WIHT_B : OFF_WIHT_F);
      const float* er = ws + OFF_EMB + (size_t)(d ? (1023 - tt) : tt) * 128;
      float acc = d ? (ebib[g] + ebhb[g]) : (ebif[g] + ebhf[g]);
#pragma unroll 4
      for (int k = 0; k < 128; ++k) acc += er[k] * wT[(size_t)k * 640 + g];
      ws[OFF_XG + idx] = acc;
    }
  }
  bt += 256; gbar_full(bar, bt);

  // ======== Stage B: encoder (blocks 0,1) || out_proj GEMM (blocks 2..255) ========
  if (bid < 2) {
    const int dir = bid;
    const float* whh = dir ? whh_b : whh_f;
    const float* xg = ws + OFF_XG + (size_t)dir * 655360;
    const int q = tid & 127, kg = tid >> 7, ks = kg * 40;
    float w[5][40];
#pragma unroll
    for (int j = 0; j < 5; ++j)
#pragma unroll
      for (int i = 0; i < 40; ++i)
        w[j][i] = whh[(size_t)(5 * q + j) * 160 + ks + i];
    float cst = 0.f;
    if (tid < 160) hbuf[tid] = 0.f;
    __syncthreads();
    for (int t = 0; t < 1024; ++t) {
      float acc[5] = {0.f, 0.f, 0.f, 0.f, 0.f};
#pragma unroll
      for (int i4 = 0; i4 < 10; ++i4) {
        float4 h4 = *(const float4*)&hbuf[ks + i4 * 4];
#pragma unroll
        for (int j = 0; j < 5; ++j)
          acc[j] += w[j][i4 * 4 + 0] * h4.x + w[j][i4 * 4 + 1] * h4.y + w[j][i4 * 4 + 2] * h4.z + w[j][i4 * 4 + 3] * h4.w;
      }
#pragma unroll
      for (int j = 0; j < 5; ++j) part[kg * 640 + 5 * q + j] = acc[j];
      __syncthreads();
      if (tid < 160) {
        float gi = xg[(size_t)t * 640 + tid];
        float gf = xg[(size_t)t * 640 + 160 + tid];
        float gg = xg[(size_t)t * 640 + 320 + tid];
        float go = xg[(size_t)t * 640 + 480 + tid];
#pragma unroll
        for (int k2 = 0; k2 < 4; ++k2) {
          gi += part[k2 * 640 + tid]; gf += part[k2 * 640 + 160 + tid];
          gg += part[k2 * 640 + 320 + tid]; go += part[k2 * 640 + 480 + tid];
        }
        cst = sigmf(gf) * cst + sigmf(gi) * tanhf(gg);
        float hn = sigmf(go) * tanhf(cst);
        hbuf[tid] = hn;
        int trow = dir ? (1023 - t) : t;
        ws[OFF_ENCH + (size_t)trow * 320 + dir * 160 + tid] = hn;
      }
      __syncthreads();
    }
    if (tid < 160) ws[OFF_H0 + dir * 160 + tid] = hbuf[tid];
  } else {
    unsigned short* Wo = (unsigned short*)(ws + OFF_WBF16);
    const int mi = tid >> 4, ni = tid & 15;
    for (int tile = bid - 2; tile < 786 * 15; tile += 254) {
      int v0 = (tile % 786) * 64, n0 = (tile / 786) * 64;
      __syncthreads();
#pragma unroll
      for (int c = 0; c < 16; ++c) {
        int idx = c * 512 + tid;
        int m = idx >> 7, k = idx & 127;
        As[m * 129 + k] = (v0 + m < VOCAB) ? embt[(size_t)(v0 + m) * 128 + k] : 0.f;
      }
      float acc[2][4] = {};
      for (int half = 0; half < 2; ++half) {
        __syncthreads();
#pragma unroll
        for (int c = 0; c < 8; ++c) {
          int idx = c * 512 + tid;
          int k = idx >> 6, n = idx & 63;
          Bs[k * 64 + n] = vp[(size_t)(half * 64 + k) * 960 + n0 + n];
        }
        __syncthreads();
        for (int k = 0; k < 64; ++k) {
          float a0 = As[(mi * 2) * 129 + half * 64 + k];
          float a1 = As[(mi * 2 + 1) * 129 + half * 64 + k];
          float4 b = *(const float4*)&Bs[k * 64 + ni * 4];
          acc[0][0] += a0 * b.x; acc[0][1] += a0 * b.y; acc[0][2] += a0 * b.z; acc[0][3] += a0 * b.w;
          acc[1][0] += a1 * b.x; acc[1][1] += a1 * b.y; acc[1][2] += a1 * b.z; acc[1][3] += a1 * b.w;
        }
      }
#pragma unroll
      for (int i = 0; i < 2; ++i) {
        int v = v0 + mi * 2 + i;
        if (v < VOCAB) {
          ushort4 pk;
          pk.x = bf16r(tanhf(acc[i][0])); pk.y = bf16r(tanhf(acc[i][1]));
          pk.z = bf16r(tanhf(acc[i][2])); pk.w = bf16r(tanhf(acc[i][3]));
          *(ushort4*)&Wo[(size_t)v * 960 + n0 + ni * 4] = pk;
        }
      }
    }
  }
  bt += 256; gbar_full(bar, bt);

  // ======== Stage C: enc_proj_h + h0 init + id sort (block 0) ========
  if (tid < 320) {
    for (int r = 0; r < 4; ++r) {
      int s = bid * 4 + r;
      const float* er = ws + OFF_ENCH + (size_t)s * 320;
      const float* wt = ws + OFF_WTE;
      float acc = 0.f;
#pragma unroll 4
      for (int k = 0; k < 320; ++k) acc += er[k] * wt[(size_t)k * 320 + tid];
      ws[OFF_EPH + (size_t)s * 320 + tid] = acc;
    }
    concatL[tid] = ws[OFF_H0 + tid];
  }
  __syncthreads();
  if (bid == 0) {
    int* sk = (int*)POOL;
    int* sp = (int*)POOL + 1024;
    for (int j = tid; j < 1024; j += 512) { sk[j] = ids[j]; sp[j] = j; }
    __syncthreads();
    for (int k = 2; k <= 1024; k <<= 1)
      for (int j = k >> 1; j > 0; j >>= 1) {
        for (int i = tid; i < 1024; i += 512) {
          int ixj = i ^ j;
          if (ixj > i) {
            bool up = ((i & k) == 0);
            int a = sk[i], b2 = sk[ixj];
            if (up ? (a > b2) : (a < b2)) {
              sk[i] = b2; sk[ixj] = a;
              int pa = sp[i]; sp[i] = sp[ixj]; sp[ixj] = pa;
            }
          }
        }
        __syncthreads();
      }
    int* BST = (int*)(ws + OFF_BSTART);
    int* SK = (int*)(ws + OFF_SKEY);
    int* SP = (int*)(ws + OFF_SPOS);
    for (int j = tid; j < 1024; j += 512) {
      SK[j] = sk[j]; SP[j] = sp[j];
      int o1 = sk[j] / VPB;
      int o0 = (j == 0) ? -1 : (sk[j - 1] / VPB);
      for (int o = o0 + 1; o <= o1; ++o) BST[o] = j;
    }
    if (tid == 0) {
      int olast = sk[1023] / VPB;
      for (int o = olast + 1; o <= 256; ++o) BST[o] = 1024;
    }
  }
  bt += 256; gbar_full(bar, bt);

  // ======== decode loop ========
  const unsigned* W = (const unsigned*)(ws + OFF_WBF16);
  const int* BST = (const int*)(ws + OFF_BSTART);
  const int* SK = (const int*)(ws + OFF_SKEY);
  const int* SP = (const int*)(ws + OFF_SPOS);
  int* AIX = (int*)(ws + OFF_AIDX);
  float creg = 0.f, cum0 = 0.f, cum1 = 0.f;
  const int vbase = bid * VPB;
  const int nv = (VOCAB - vbase < VPB) ? (VOCAB - vbase) : VPB;

  for (int t = 0; t < TDEC; ++t) {
    // ---- S0: token reduce (t>0) + gates + zero HP/CENC ----
    int token = 0;
    if (t > 0) {
      if (tid < 256) { redA[tid] = scld(ws + OFF_AVAL + tid); redI[tid] = scldi(AIX + tid); }
      __syncthreads();
      for (int off = 128; off > 0; off >>= 1) {
        if (tid < off) {
          float v2 = redA[tid + off]; int i2 = redI[tid + off];
          if (v2 > redA[tid] || (v2 == redA[tid] && i2 < redI[tid])) { redA[tid] = v2; redI[tid] = i2; }
        }
        __syncthreads();
      }
      token = redI[0];
      __syncthreads();
    }
    int tokm = (token >= VOCAB) ? UNK : token;
    if (bid < 160) {
      int g = bid * 8 + wv;
      float xv0 = embt[(size_t)tokm * 128 + l];
      float xv1 = embt[(size_t)tokm * 128 + 64 + l];
      float hv[5];
#pragma unroll
      for (int c = 0; c < 5; ++c) hv[c] = concatL[c * 64 + l];
      float acc = dwih[(size_t)g * 128 + l] * xv0 + dwih[(size_t)g * 128 + 64 + l] * xv1;
#pragma unroll
      for (int c = 0; c < 5; ++c) acc += dwhh[(size_t)g * 320 + c * 64 + l] * hv[c];
      acc = wsum64(acc);
      if (l == 0) scst(ws + OFF_GATES + g, acc + dbih[g] + dbhh[g]);
    }
    if (bid == 200 && tid < 320) scst(ws + OFF_HP + tid, 0.f);
    if (bid == 201 && tid < 320) scst(ws + OFF_CENC + tid, 0.f);
    bt += 256; gbar_lite(bar, bt);

    // ---- S1: h,c update (redundant) + fp8 decbuf append + scores + hp ----
    if (tid < 320) {
      float gi = scld(ws + OFF_GATES + tid);
      float gf = scld(ws + OFF_GATES + 320 + tid);
      float gg = scld(ws + OFF_GATES + 640 + tid);
      float go = scld(ws + OFF_GATES + 960 + tid);
      creg = sigmf(gf) * creg + sigmf(gi) * tanhf(gg);
      concatL[tid] = sigmf(go) * tanhf(creg);
    }
    __syncthreads();
    if (tid < 80) {
      int lo = __builtin_amdgcn_cvt_pk_fp8_f32(concatL[4 * tid], concatL[4 * tid + 1], 0, false);
      int both = __builtin_amdgcn_cvt_pk_fp8_f32(concatL[4 * tid + 2], concatL[4 * tid + 3], lo, true);
      decbufU[t * 80 + tid] = (unsigned)both;
    }
    if (bid < 128) {
      int g = bid * 8 + wv;
      const float* er = ws + OFF_EPH + (size_t)g * 320;
      float acc = 0.f;
#pragma unroll
      for (int c = 0; c < 5; ++c) acc += er[c * 64 + l] * concatL[c * 64 + l];
      acc = wsum64(acc);
      if (l == 0) scst(ws + OFF_SCORES + g, acc);
    }
    if (bid >= 128 && bid < 136 && tid < 320) {
      int q = bid - 128;
      float acc = 0.f;
#pragma unroll 8
      for (int ii = 0; ii < 40; ++ii) {
        int i = q * 40 + ii;
        acc += concatL[i] * dap[(size_t)i * 320 + tid];
      }
      atomicAdd(&ws[OFF_HP + tid], acc);
    }
    bt += 256; gbar_lite(bar, bt);

    // ---- S2: temporal softmax + enc_ctx partials + dec attention + dec_ctx ----
    {
      float s0 = scld(ws + OFF_SCORES + tid);
      float s1 = scld(ws + OFF_SCORES + 512 + tid);
      float t0 = (t == 0) ? s0 : expf(s0) / cum0;
      float t1 = (t == 0) ? s1 : expf(s1) / cum1;
      cum0 += s0; cum1 += s1;
      redA[tid] = fmaxf(t0, t1);
      __syncthreads();
      for (int off = 256; off > 0; off >>= 1) { if (tid < off) redA[tid] = fmaxf(redA[tid], redA[tid + off]); __syncthreads(); }
      float mx = redA[0];
      __syncthreads();
      redA[tid] = expf(t0 - mx) + expf(t1 - mx);
      __syncthreads();
      for (int off = 256; off > 0; off >>= 1) { if (tid < off) redA[tid] += redA[tid + off]; __syncthreads(); }
      float Ssm = redA[0];
      __syncthreads();
      attnL[tid] = expf(t0 - mx) / Ssm;
      attnL[512 + tid] = expf(t1 - mx) / Ssm;
      if (tid < 320) hpL[tid] = scld(ws + OFF_HP + tid);
      __syncthreads();  // attnL + hpL ready
      if (bid < 32 && tid < 320) {
        float acc = 0.f;
        const float* eh = ws + OFF_ENCH + (size_t)(bid * 32) * 320 + tid;
#pragma unroll 4
        for (int k2 = 0; k2 < 32; ++k2) acc += attnL[bid * 32 + k2] * eh[(size_t)k2 * 320];
        atomicAdd(&ws[OFF_CENC + tid], acc);
      }
      float hpv[5];
#pragma unroll
      for (int c = 0; c < 5; ++c) hpv[c] = hpL[c * 64 + l];
#pragma unroll
      for (int k2 = 0; k2 < 13; ++k2) {
        int tp = wv + 8 * k2;
        if (tp < t) {
          float acc = 0.f;
#pragma unroll
          for (int c = 0; c < 5; ++c)
            acc += hpv[c] * fp8dec(decbufU[tp * 80 + c * 16 + (l >> 2)], l & 3);
          acc = wsum64(acc);
          if (l == 0) dsL[tp] = acc;
        }
      }
      __syncthreads();
      float dv = -1e30f;
      if (tid < 128) { dv = (tid < t) ? dsL[tid] : -1e30f; redA[tid] = dv; }
      __syncthreads();
      for (int off = 64; off > 0; off >>= 1) { if (tid < off) redA[tid] = fmaxf(redA[tid], redA[tid + off]); __syncthreads(); }
      float dmx = redA[0];
      __syncthreads();
      float de = (tid < 128) ? expf(dv - dmx) : 0.f;
      if (tid < 128) redA[tid] = de;
      __syncthreads();
      for (int off = 64; off > 0; off >>= 1) { if (tid < off) redA[tid] += redA[tid + off]; __syncthreads(); }
      float dS = redA[0];
      __syncthreads();
      if (tid < 128) daL[tid] = de / dS;
      __syncthreads();
      if (tid < 320) {
        float acc = 0.f;
        for (int tp = 0; tp < t; ++tp)
          acc += daL[tp] * fp8dec(decbufU[tp * 80 + (tid >> 2)], tid & 3);
        concatL[640 + tid] = acc;
      }
    }
    bt += 256; gbar_lite(bar, bt);

    // ---- S3: assemble concat + p_copy (redundant) + block logits slice ----
    if (tid < 320) concatL[320 + tid] = scld(ws + OFF_CENC + tid);
    __syncthreads();
    if (tid < 64) {
      float acc = 0.f;
#pragma unroll
      for (int c = 0; c < 15; ++c) acc += sw[c * 64 + l] * concatL[c * 64 + l];
      acc = wsum64(acc);
      if (l == 0) scalL[0] = 1.f / (1.f + expf(-(acc + sb[0])));
    }
    {
      const float2* cL2 = (const float2*)concatL;
      float cc0[7], cc1[7], ct0 = 0.f, ct1 = 0.f;
#pragma unroll
      for (int c = 0; c < 7; ++c) { float2 x = cL2[c * 64 + l]; cc0[c] = x.x; cc1[c] = x.y; }
      if (l < 32) { ct0 = concatL[896 + 2 * l]; ct1 = concatL[897 + 2 * l]; }
      const int rend = (wv * 25 + 25 < 197) ? (wv * 25 + 25) : 197;
      for (int r = wv * 25; r < rend; ++r) {
        int v = vbase + r;
        if (v < VOCAB) {
          const unsigned* row = W + (size_t)v * 480;
          float acc = 0.f;
#pragma unroll
          for (int c = 0; c < 7; ++c) {
            unsigned u = row[c * 64 + l];
            acc += __uint_as_float(u << 16) * cc0[c] + __uint_as_float(u & 0xffff0000u) * cc1[c];
          }
          if (l < 32) {
            unsigned u = row[448 + l];
            acc += __uint_as_float(u << 16) * ct0 + __uint_as_float(u & 0xffff0000u) * ct1;
          }
          acc = wsum64(acc);
          if (l == 0) logitsL[r] = acc + ob[v];
        }
      }
      __syncthreads();
      float lv = (tid < nv) ? logitsL[tid] : -1e30f;
      redA[tid] = lv;
      __syncthreads();
      for (int off = 256; off > 0; off >>= 1) { if (tid < off) redA[tid] = fmaxf(redA[tid], redA[tid + off]); __syncthreads(); }
      float bmx = redA[0];
      __syncthreads();
      redA[tid] = (tid < nv) ? expf(lv - bmx) : 0.f;
      __syncthreads();
      for (int off = 256; off > 0; off >>= 1) { if (tid < off) redA[tid] += redA[tid + off]; __syncthreads(); }
      if (tid == 0) { scst(ws + OFF_BM + bid, bmx); scst(ws + OFF_BS + bid, redA[0]); }
    }
    bt += 256; gbar_lite(bar, bt);

    // ---- S4: global softmax combine + final write + scatter + argmax partial ----
    {
      if (tid < 256) { redA[tid] = scld(ws + OFF_BM + tid); redB[tid] = scld(ws + OFF_BS + tid); }
      __syncthreads();
      for (int off = 128; off > 0; off >>= 1) {
        if (tid < off) {
          float m1 = redA[tid], m2 = redA[tid + off];
          float mm = fmaxf(m1, m2);
          redB[tid] = redB[tid] * expf(m1 - mm) + redB[tid + off] * expf(m2 - mm);
          redA[tid] = mm;
        }
        __syncthreads();
      }
      float M = redA[0], Sg = redB[0];
      float pc = scalL[0];
      float scale = (1.f - pc) / Sg;
      int v = vbase + tid;
      bool act = (tid < VPB) && (v < VTOT);
      float val = -1e30f;
      if (act) {
        val = (v < VOCAB) ? scale * expf(logitsL[tid] - M) : 0.f;
        int jb = BST[bid], je = BST[bid + 1];
        for (int j = jb; j < je; ++j)
          if (SK[j] == v) val += pc * attnL[SP[j]];
        out[(size_t)t * VTOT + v] = val;
      }
      __syncthreads();
      redA[tid] = act ? val : -1e30f; redI[tid] = v;
      __syncthreads();
      for (int off = 256; off > 0; off >>= 1) {
        if (tid < off) {
          float v2 = redA[tid + off]; int i2 = redI[tid + off];
          if (v2 > redA[tid] || (v2 == redA[tid] && i2 < redI[tid])) { redA[tid] = v2; redI[tid] = i2; }
        }
        __syncthreads();
      }
      if (tid == 0) { scst(ws + OFF_AVAL + bid, redA[0]); scsti(AIX + bid, redI[0]); }
    }
    bt += 256; gbar_lite(bar, bt);
  }
}

// ---------------- host ----------------
extern "C" void kernel_launch(void* const* d_in, const int* in_sizes, int n_in,
                              void* d_out, int out_size, void* d_ws, size_t ws_size,
                              hipStream_t stream) {
  const int*   ids  = (const int*)d_in[0];
  const float* embt = (const float*)d_in[1];
  const float* ewf  = (const float*)d_in[2];
  const float* ehf  = (const float*)d_in[3];
  const float* ebif = (const float*)d_in[4];
  const float* ebhf = (const float*)d_in[5];
  const float* ewb  = (const float*)d_in[6];
  const float* ehb  = (const float*)d_in[7];
  const float* ebib = (const float*)d_in[8];
  const float* ebhb = (const float*)d_in[9];
  const float* dwih = (const float*)d_in[10];
  const float* dwhh = (const float*)d_in[11];
  const float* dbih = (const float*)d_in[12];
  const float* dbhh = (const float*)d_in[13];
  const float* eap  = (const float*)d_in[14];
  const float* dap  = (const float*)d_in[15];
  const float* vp   = (const float*)d_in[16];
  const float* ob   = (const float*)d_in[17];
  const float* sw   = (const float*)d_in[18];
  const float* sb   = (const float*)d_in[19];
  float* out = (float*)d_out;
  float* ws  = (float*)d_ws;

  k_setup<<<1552, 256, 0, stream>>>(ws, ids, embt, ewf, ewb, eap);
  k_fused<<<256, 512, 0, stream>>>(ws, out, ids, embt, dwih, dwhh, dbih, dbhh,
                                   dap, ob, sw, sb, ebif, ebhf, ebib, ebhb,
                                   ehf, ehb, vp);
}

// Round 4
// 22181.721 us; speedup vs baseline: 1.9996x; 1.0577x over previous
//
#include <hip/hip_runtime.h>
#include <cstdint>

#define VOCAB 50257
#define VTOT  50321
#define TDEC  100
#define UNK   3
#define VPB   197          // vocab slice per block (197*256=50432 >= 50321)

// ---------------- workspace layout (float offsets) ----------------
static const size_t OFF_EMB    = 0;        // [1024][128]
static const size_t OFF_WIHT_F = 131072;   // [128][640]
static const size_t OFF_WIHT_B = 212992;   // [128][640]
static const size_t OFF_WTE    = 294912;   // [320][320]  enc_attn_proj^T
static const size_t OFF_XG     = 397312;   // [2][1024][640]
static const size_t OFF_ENCH   = 1708032;  // [1024][320]
static const size_t OFF_EPH    = 2035712;  // [1024][320]
static const size_t OFF_SCORES = 2445664;  // 1024
static const size_t OFF_HP     = 2446688;  // 320
static const size_t OFF_CENC   = 2447008;  // 320
static const size_t OFF_GATES  = 2447328;  // 1280
static const size_t OFF_BM     = 2448608;  // 256
static const size_t OFF_BS     = 2448864;  // 256
static const size_t OFF_AVAL   = 2449120;  // 256
static const size_t OFF_AIDX   = 2449376;  // 256 (int)
static const size_t OFF_H0     = 2449632;  // 320
static const size_t OFF_SKEY   = 2449984;  // 1024 (int)
static const size_t OFF_SPOS   = 2451008;  // 1024 (int)
static const size_t OFF_BSTART = 2452032;  // 257 (int)
static const size_t OFF_WBF16  = 2452352;  // bf16 out_proj, 50257*480 u32
static const size_t OFF_GARR   = 26575712; // 64 lines x 32 u32 (arrival counters)
static const size_t OFF_GOPR   = 26577760; // 256 lines x 32 u32 (private go words)

__device__ __forceinline__ float sigmf(float x) { return 1.f / (1.f + expf(-x)); }

__device__ __forceinline__ float wsum64(float x) {
#pragma unroll
  for (int m = 1; m < 64; m <<= 1) x += __shfl_xor(x, m, 64);
  return x;
}

__device__ __forceinline__ unsigned short bf16r(float x) {
  uint32_t b = __float_as_uint(x);
  uint32_t r = (b + 0x7fffu + ((b >> 16) & 1u)) >> 16;
  return (unsigned short)r;
}

// agent-scope accesses: coherent across XCDs, bypass stale L1/L2 copies
__device__ __forceinline__ float scld(const float* p) {
  return __hip_atomic_load(p, __ATOMIC_RELAXED, __HIP_MEMORY_SCOPE_AGENT);
}
__device__ __forceinline__ int scldi(const int* p) {
  return __hip_atomic_load(p, __ATOMIC_RELAXED, __HIP_MEMORY_SCOPE_AGENT);
}
__device__ __forceinline__ unsigned scldu(const unsigned* p) {
  return __hip_atomic_load(p, __ATOMIC_RELAXED, __HIP_MEMORY_SCOPE_AGENT);
}
__device__ __forceinline__ void scst(float* p, float v) {
  __hip_atomic_store(p, v, __ATOMIC_RELAXED, __HIP_MEMORY_SCOPE_AGENT);
}
__device__ __forceinline__ void scsti(int* p, int v) {
  __hip_atomic_store(p, v, __ATOMIC_RELAXED, __HIP_MEMORY_SCOPE_AGENT);
}
__device__ __forceinline__ void scstu(unsigned* p, unsigned v) {
  __hip_atomic_store(p, v, __ATOMIC_RELAXED, __HIP_MEMORY_SCOPE_AGENT);
}

__device__ __forceinline__ float fp8dec(unsigned w, int sel) {
  return __builtin_amdgcn_cvt_f32_fp8((int)((w >> (sel * 8)) & 0xffu), 0);
}

// Fan-in/fan-out grid barrier: arrivals spread over 64 lines (4 blocks/line),
// leader block (bid 0) wave-0 polls all 64 lines in parallel, then 255 leader
// threads write per-block private go-words (1 poller per line). No hot line.
__device__ __forceinline__ void gbar(unsigned* grr, unsigned* gop, unsigned ep,
                                     int bid, int tid) {
  __syncthreads();  // all prior stores drained (vmcnt(0) before s_barrier)
  if (tid == 0)
    __hip_atomic_fetch_add(grr + (bid & 63) * 32, 1u, __ATOMIC_RELAXED, __HIP_MEMORY_SCOPE_AGENT);
  if (bid == 0) {
    if (tid < 64) {
      unsigned need = 4u * ep;
      while (scldu(grr + tid * 32) < need) __builtin_amdgcn_s_sleep(4);
    }
    __syncthreads();  // wave 0 done => all 256 arrived
    if (tid >= 1 && tid < 256) scstu(gop + tid * 32, ep);
    __syncthreads();
  } else {
    if (tid == 0) {
      while (scldu(gop + bid * 32) < ep) __builtin_amdgcn_s_sleep(4);
    }
    __syncthreads();
  }
}

__device__ __forceinline__ void gbar_full(unsigned* grr, unsigned* gop, unsigned ep,
                                          int bid, int tid) {
  __threadfence();
  gbar(grr, gop, ep, bid, tid);
  __threadfence();
}

// ---------------- setup: embedding gather, weight transposes, barrier reset ----------------
__global__ __launch_bounds__(256) void k_setup(float* __restrict__ ws, const int* __restrict__ ids,
                                               const float* __restrict__ embt, const float* __restrict__ ewf,
                                               const float* __restrict__ ewb, const float* __restrict__ eap) {
  int idx = blockIdx.x * 256 + threadIdx.x;
  if (idx < 131072) {
    int tt = idx >> 7, e = idx & 127;
    int id = ids[tt]; if (id >= VOCAB) id = UNK;
    ws[OFF_EMB + idx] = embt[(size_t)id * 128 + e];
  } else if (idx < 212992) {
    int i = idx - 131072;
    int k = i / 640, g = i - (i / 640) * 640;
    ws[OFF_WIHT_F + i] = ewf[(size_t)g * 128 + k];
  } else if (idx < 294912) {
    int i = idx - 212992;
    int k = i / 640, g = i - (i / 640) * 640;
    ws[OFF_WIHT_B + i] = ewb[(size_t)g * 128 + k];
  } else if (idx < 397312) {
    int i = idx - 294912;
    int k = i / 320, j = i - (i / 320) * 320;
    ws[OFF_WTE + i] = eap[(size_t)j * 320 + k];
  } else if (idx < 407552) {
    ((unsigned*)ws)[OFF_GARR + (idx - 397312)] = 0u;  // GARR + GOPR contiguous
  }
}

// ---------------- fused persistent kernel ----------------
__global__ __launch_bounds__(512, 2) void k_fused(
    float* __restrict__ ws, float* __restrict__ out, const int* __restrict__ ids,
    const float* __restrict__ embt,
    const float* __restrict__ dwih, const float* __restrict__ dwhh,
    const float* __restrict__ dbih, const float* __restrict__ dbhh,
    const float* __restrict__ dap, const float* __restrict__ ob,
    const float* __restrict__ sw, const float* __restrict__ sb,
    const float* __restrict__ ebif, const float* __restrict__ ebhf,
    const float* __restrict__ ebib, const float* __restrict__ ebhb,
    const float* __restrict__ whh_f, const float* __restrict__ whh_b,
    const float* __restrict__ vp) {
  __shared__ float POOL[12352];  // 49.4 KB
  unsigned* decbufU = (unsigned*)POOL;       // [100][80] u32 = fp8 x4 (32 KB)
  float* attnL   = POOL + 8000;   // 1024
  float* concatL = POOL + 9024;   // 960  [h | enc_ctx | dec_ctx]
  float* redA    = POOL + 9984;   // 512
  float* redB    = POOL + 10496;  // 512
  int*   redI    = (int*)(POOL + 11008); // 512
  float* dsL     = POOL + 11520;  // 128
  float* daL     = POOL + 11648;  // 128
  float* logitsL = POOL + 11776;  // 200
  float* hpL     = POOL + 11976;  // 320
  float* scalL   = POOL + 12296;  // 1
  // prologue aliases
  float* As   = POOL;             // 64x129
  float* Bs   = POOL + 8256;      // 64x64
  float* hbuf = POOL;             // 160
  float* part = POOL + 160;       // 4x640

  const int tid = threadIdx.x, bid = blockIdx.x;
  const int l = tid & 63, wv = tid >> 6;
  unsigned* grr = (unsigned*)ws + OFF_GARR;
  unsigned* gop = (unsigned*)ws + OFF_GOPR;
  unsigned ep = 0;

  // ======== Stage A: encoder x-part gates ========
  {
    const int base = bid * 512 + tid;
#pragma unroll
    for (int i = 0; i < 10; ++i) {
      int idx = i * 131072 + base;
      int d = idx / 655360;
      int r = idx - d * 655360;
      int tt = r / 640, g = r - (r / 640) * 640;
      const float* wT = ws + (d ? OFF_WIHT_B : OFF_WIHT_F);
      const float* er = ws + OFF_EMB + (size_t)(d ? (1023 - tt) : tt) * 128;
      float acc = d ? (ebib[g] + ebhb[g]) : (ebif[g] + ebhf[g]);
#pragma unroll 4
      for (int k = 0; k < 128; ++k) acc += er[k] * wT[(size_t)k * 640 + g];
      ws[OFF_XG + idx] = acc;
    }
  }
  ++ep; gbar_full(grr, gop, ep, bid, tid);

  // ======== Stage B: encoder (blocks 0,1) || out_proj GEMM (blocks 2..255) ========
  if (bid < 2) {
    const int dir = bid;
    const float* whh = dir ? whh_b : whh_f;
    const float* xg = ws + OFF_XG + (size_t)dir * 655360;
    const int q = tid & 127, kg = tid >> 7, ks = kg * 40;
    float w[5][40];
#pragma unroll
    for (int j = 0; j < 5; ++j)
#pragma unroll
      for (int i = 0; i < 40; ++i)
        w[j][i] = whh[(size_t)(5 * q + j) * 160 + ks + i];
    float cst = 0.f;
    if (tid < 160) hbuf[tid] = 0.f;
    __syncthreads();
    for (int t = 0; t < 1024; ++t) {
      float acc[5] = {0.f, 0.f, 0.f, 0.f, 0.f};
#pragma unroll
      for (int i4 = 0; i4 < 10; ++i4) {
        float4 h4 = *(const float4*)&hbuf[ks + i4 * 4];
#pragma unroll
        for (int j = 0; j < 5; ++j)
          acc[j] += w[j][i4 * 4 + 0] * h4.x + w[j][i4 * 4 + 1] * h4.y + w[j][i4 * 4 + 2] * h4.z + w[j][i4 * 4 + 3] * h4.w;
      }
#pragma unroll
      for (int j = 0; j < 5; ++j) part[kg * 640 + 5 * q + j] = acc[j];
      __syncthreads();
      if (tid < 160) {
        float gi = xg[(size_t)t * 640 + tid];
        float gf = xg[(size_t)t * 640 + 160 + tid];
        float gg = xg[(size_t)t * 640 + 320 + tid];
        float go = xg[(size_t)t * 640 + 480 + tid];
#pragma unroll
        for (int k2 = 0; k2 < 4; ++k2) {
          gi += part[k2 * 640 + tid]; gf += part[k2 * 640 + 160 + tid];
          gg += part[k2 * 640 + 320 + tid]; go += part[k2 * 640 + 480 + tid];
        }
        cst = sigmf(gf) * cst + sigmf(gi) * tanhf(gg);
        float hn = sigmf(go) * tanhf(cst);
        hbuf[tid] = hn;
        int trow = dir ? (1023 - t) : t;
        ws[OFF_ENCH + (size_t)trow * 320 + dir * 160 + tid] = hn;
      }
      __syncthreads();
    }
    if (tid < 160) ws[OFF_H0 + dir * 160 + tid] = hbuf[tid];
  } else {
    unsigned short* Wo = (unsigned short*)(ws + OFF_WBF16);
    const int mi = tid >> 4, ni = tid & 15;
    for (int tile = bid - 2; tile < 786 * 15; tile += 254) {
      int v0 = (tile % 786) * 64, n0 = (tile / 786) * 64;
      __syncthreads();
#pragma unroll
      for (int c = 0; c < 16; ++c) {
        int idx = c * 512 + tid;
        int m = idx >> 7, k = idx & 127;
        As[m * 129 + k] = (v0 + m < VOCAB) ? embt[(size_t)(v0 + m) * 128 + k] : 0.f;
      }
      float acc[2][4] = {};
      for (int half = 0; half < 2; ++half) {
        __syncthreads();
#pragma unroll
        for (int c = 0; c < 8; ++c) {
          int idx = c * 512 + tid;
          int k = idx >> 6, n = idx & 63;
          Bs[k * 64 + n] = vp[(size_t)(half * 64 + k) * 960 + n0 + n];
        }
        __syncthreads();
        for (int k = 0; k < 64; ++k) {
          float a0 = As[(mi * 2) * 129 + half * 64 + k];
          float a1 = As[(mi * 2 + 1) * 129 + half * 64 + k];
          float4 b = *(const float4*)&Bs[k * 64 + ni * 4];
          acc[0][0] += a0 * b.x; acc[0][1] += a0 * b.y; acc[0][2] += a0 * b.z; acc[0][3] += a0 * b.w;
          acc[1][0] += a1 * b.x; acc[1][1] += a1 * b.y; acc[1][2] += a1 * b.z; acc[1][3] += a1 * b.w;
        }
      }
#pragma unroll
      for (int i = 0; i < 2; ++i) {
        int v = v0 + mi * 2 + i;
        if (v < VOCAB) {
          ushort4 pk;
          pk.x = bf16r(tanhf(acc[i][0])); pk.y = bf16r(tanhf(acc[i][1]));
          pk.z = bf16r(tanhf(acc[i][2])); pk.w = bf16r(tanhf(acc[i][3]));
          *(ushort4*)&Wo[(size_t)v * 960 + n0 + ni * 4] = pk;
        }
      }
    }
  }
  ++ep; gbar_full(grr, gop, ep, bid, tid);

  // ======== Stage C: enc_proj_h + h0 init + id sort (block 0) ========
  if (tid < 320) {
    for (int r = 0; r < 4; ++r) {
      int s = bid * 4 + r;
      const float* er = ws + OFF_ENCH + (size_t)s * 320;
      const float* wt = ws + OFF_WTE;
      float acc = 0.f;
#pragma unroll 4
      for (int k = 0; k < 320; ++k) acc += er[k] * wt[(size_t)k * 320 + tid];
      ws[OFF_EPH + (size_t)s * 320 + tid] = acc;
    }
    concatL[tid] = ws[OFF_H0 + tid];
  }
  __syncthreads();
  if (bid == 0) {
    int* sk = (int*)POOL;
    int* sp = (int*)POOL + 1024;
    for (int j = tid; j < 1024; j += 512) { sk[j] = ids[j]; sp[j] = j; }
    __syncthreads();
    for (int k = 2; k <= 1024; k <<= 1)
      for (int j = k >> 1; j > 0; j >>= 1) {
        for (int i = tid; i < 1024; i += 512) {
          int ixj = i ^ j;
          if (ixj > i) {
            bool up = ((i & k) == 0);
            int a = sk[i], b2 = sk[ixj];
            if (up ? (a > b2) : (a < b2)) {
              sk[i] = b2; sk[ixj] = a;
              int pa = sp[i]; sp[i] = sp[ixj]; sp[ixj] = pa;
            }
          }
        }
        __syncthreads();
      }
    int* BST = (int*)(ws + OFF_BSTART);
    int* SK = (int*)(ws + OFF_SKEY);
    int* SP = (int*)(ws + OFF_SPOS);
    for (int j = tid; j < 1024; j += 512) {
      SK[j] = sk[j]; SP[j] = sp[j];
      int o1 = sk[j] / VPB;
      int o0 = (j == 0) ? -1 : (sk[j - 1] / VPB);
      for (int o = o0 + 1; o <= o1; ++o) BST[o] = j;
    }
    if (tid == 0) {
      int olast = sk[1023] / VPB;
      for (int o = olast + 1; o <= 256; ++o) BST[o] = 1024;
    }
  }
  ++ep; gbar_full(grr, gop, ep, bid, tid);

  // ======== decode loop ========
  const unsigned* W = (const unsigned*)(ws + OFF_WBF16);
  const int* BST = (const int*)(ws + OFF_BSTART);
  const int* SK = (const int*)(ws + OFF_SKEY);
  const int* SP = (const int*)(ws + OFF_SPOS);
  int* AIX = (int*)(ws + OFF_AIDX);
  float creg = 0.f, cum0 = 0.f, cum1 = 0.f;
  const int vbase = bid * VPB;
  const int nv = (VOCAB - vbase < VPB) ? (VOCAB - vbase) : VPB;

  for (int t = 0; t < TDEC; ++t) {
    // ---- S0: token reduce (t>0) + gates + zero HP/CENC ----
    int token = 0;
    if (t > 0) {
      if (tid < 256) { redA[tid] = scld(ws + OFF_AVAL + tid); redI[tid] = scldi(AIX + tid); }
      __syncthreads();
      for (int off = 128; off > 0; off >>= 1) {
        if (tid < off) {
          float v2 = redA[tid + off]; int i2 = redI[tid + off];
          if (v2 > redA[tid] || (v2 == redA[tid] && i2 < redI[tid])) { redA[tid] = v2; redI[tid] = i2; }
        }
        __syncthreads();
      }
      token = redI[0];
      __syncthreads();
    }
    int tokm = (token >= VOCAB) ? UNK : token;
    if (bid < 160) {
      int g = bid * 8 + wv;
      float xv0 = embt[(size_t)tokm * 128 + l];
      float xv1 = embt[(size_t)tokm * 128 + 64 + l];
      float hv[5];
#pragma unroll
      for (int c = 0; c < 5; ++c) hv[c] = concatL[c * 64 + l];
      float acc = dwih[(size_t)g * 128 + l] * xv0 + dwih[(size_t)g * 128 + 64 + l] * xv1;
#pragma unroll
      for (int c = 0; c < 5; ++c) acc += dwhh[(size_t)g * 320 + c * 64 + l] * hv[c];
      acc = wsum64(acc);
      if (l == 0) scst(ws + OFF_GATES + g, acc + dbih[g] + dbhh[g]);
    }
    if (bid == 200 && tid < 320) scst(ws + OFF_HP + tid, 0.f);
    if (bid == 201 && tid < 320) scst(ws + OFF_CENC + tid, 0.f);
    ++ep; gbar(grr, gop, ep, bid, tid);

    // ---- S1: h,c update (redundant) + fp8 decbuf append + scores + hp ----
    if (tid < 320) {
      float gi = scld(ws + OFF_GATES + tid);
      float gf = scld(ws + OFF_GATES + 320 + tid);
      float gg = scld(ws + OFF_GATES + 640 + tid);
      float go = scld(ws + OFF_GATES + 960 + tid);
      creg = sigmf(gf) * creg + sigmf(gi) * tanhf(gg);
      concatL[tid] = sigmf(go) * tanhf(creg);
    }
    __syncthreads();
    if (tid < 80) {
      int lo = __builtin_amdgcn_cvt_pk_fp8_f32(concatL[4 * tid], concatL[4 * tid + 1], 0, false);
      int both = __builtin_amdgcn_cvt_pk_fp8_f32(concatL[4 * tid + 2], concatL[4 * tid + 3], lo, true);
      decbufU[t * 80 + tid] = (unsigned)both;
    }
    if (bid < 128) {
      int g = bid * 8 + wv;
      const float* er = ws + OFF_EPH + (size_t)g * 320;
      float acc = 0.f;
#pragma unroll
      for (int c = 0; c < 5; ++c) acc += er[c * 64 + l] * concatL[c * 64 + l];
      acc = wsum64(acc);
      if (l == 0) scst(ws + OFF_SCORES + g, acc);
    }
    if (bid >= 128 && bid < 136 && tid < 320) {
      int q = bid - 128;
      float acc = 0.f;
#pragma unroll 8
      for (int ii = 0; ii < 40; ++ii) {
        int i = q * 40 + ii;
        acc += concatL[i] * dap[(size_t)i * 320 + tid];
      }
      atomicAdd(&ws[OFF_HP + tid], acc);
    }
    ++ep; gbar(grr, gop, ep, bid, tid);

    // ---- S2: temporal softmax + enc_ctx partials + dec attention + dec_ctx ----
    {
      float s0 = scld(ws + OFF_SCORES + tid);
      float s1 = scld(ws + OFF_SCORES + 512 + tid);
      float t0 = (t == 0) ? s0 : expf(s0) / cum0;
      float t1 = (t == 0) ? s1 : expf(s1) / cum1;
      cum0 += s0; cum1 += s1;
      redA[tid] = fmaxf(t0, t1);
      __syncthreads();
      for (int off = 256; off > 0; off >>= 1) { if (tid < off) redA[tid] = fmaxf(redA[tid], redA[tid + off]); __syncthreads(); }
      float mx = redA[0];
      __syncthreads();
      redA[tid] = expf(t0 - mx) + expf(t1 - mx);
      __syncthreads();
      for (int off = 256; off > 0; off >>= 1) { if (tid < off) redA[tid] += redA[tid + off]; __syncthreads(); }
      float Ssm = redA[0];
      __syncthreads();
      attnL[tid] = expf(t0 - mx) / Ssm;
      attnL[512 + tid] = expf(t1 - mx) / Ssm;
      if (tid < 320) hpL[tid] = scld(ws + OFF_HP + tid);
      __syncthreads();  // attnL + hpL ready
      if (bid < 32 && tid < 320) {
        float acc = 0.f;
        const float* eh = ws + OFF_ENCH + (size_t)(bid * 32) * 320 + tid;
#pragma unroll 4
        for (int k2 = 0; k2 < 32; ++k2) acc += attnL[bid * 32 + k2] * eh[(size_t)k2 * 320];
        atomicAdd(&ws[OFF_CENC + tid], acc);
      }
      float hpv[5];
#pragma unroll
      for (int c = 0; c < 5; ++c) hpv[c] = hpL[c * 64 + l];
#pragma unroll
      for (int k2 = 0; k2 < 13; ++k2) {
        int tp = wv + 8 * k2;
        if (tp < t) {
          float acc = 0.f;
#pragma unroll
          for (int c = 0; c < 5; ++c)
            acc += hpv[c] * fp8dec(decbufU[tp * 80 + c * 16 + (l >> 2)], l & 3);
          acc = wsum64(acc);
          if (l == 0) dsL[tp] = acc;
        }
      }
      __syncthreads();
      float dv = -1e30f;
      if (tid < 128) { dv = (tid < t) ? dsL[tid] : -1e30f; redA[tid] = dv; }
      __syncthreads();
      for (int off = 64; off > 0; off >>= 1) { if (tid < off) redA[tid] = fmaxf(redA[tid], redA[tid + off]); __syncthreads(); }
      float dmx = redA[0];
      __syncthreads();
      float de = (tid < 128) ? expf(dv - dmx) : 0.f;
      if (tid < 128) redA[tid] = de;
      __syncthreads();
      for (int off = 64; off > 0; off >>= 1) { if (tid < off) redA[tid] += redA[tid + off]; __syncthreads(); }
      float dS = redA[0];
      __syncthreads();
      if (tid < 128) daL[tid] = de / dS;
      __syncthreads();
      if (tid < 320) {
        float acc = 0.f;
        for (int tp = 0; tp < t; ++tp)
          acc += daL[tp] * fp8dec(decbufU[tp * 80 + (tid >> 2)], tid & 3);
        concatL[640 + tid] = acc;
      }
    }
    ++ep; gbar(grr, gop, ep, bid, tid);

    // ---- S3: assemble concat + p_copy (redundant) + block logits slice ----
    if (tid < 320) concatL[320 + tid] = scld(ws + OFF_CENC + tid);
    __syncthreads();
    if (tid < 64) {
      float acc = 0.f;
#pragma unroll
      for (int c = 0; c < 15; ++c) acc += sw[c * 64 + l] * concatL[c * 64 + l];
      acc = wsum64(acc);
      if (l == 0) scalL[0] = 1.f / (1.f + expf(-(acc + sb[0])));
    }
    {
      const float2* cL2 = (const float2*)concatL;
      float cc0[7], cc1[7], ct0 = 0.f, ct1 = 0.f;
#pragma unroll
      for (int c = 0; c < 7; ++c) { float2 x = cL2[c * 64 + l]; cc0[c] = x.x; cc1[c] = x.y; }
      if (l < 32) { ct0 = concatL[896 + 2 * l]; ct1 = concatL[897 + 2 * l]; }
      const int rend = (wv * 25 + 25 < 197) ? (wv * 25 + 25) : 197;
      for (int r = wv * 25; r < rend; ++r) {
        int v = vbase + r;
        if (v < VOCAB) {
          const unsigned* row = W + (size_t)v * 480;
          float acc = 0.f;
#pragma unroll
          for (int c = 0; c < 7; ++c) {
            unsigned u = row[c * 64 + l];
            acc += __uint_as_float(u << 16) * cc0[c] + __uint_as_float(u & 0xffff0000u) * cc1[c];
          }
          if (l < 32) {
            unsigned u = row[448 + l];
            acc += __uint_as_float(u << 16) * ct0 + __uint_as_float(u & 0xffff0000u) * ct1;
          }
          acc = wsum64(acc);
          if (l == 0) logitsL[r] = acc + ob[v];
        }
      }
      __syncthreads();
      float lv = (tid < nv) ? logitsL[tid] : -1e30f;
      redA[tid] = lv;
      __syncthreads();
      for (int off = 256; off > 0; off >>= 1) { if (tid < off) redA[tid] = fmaxf(redA[tid], redA[tid + off]); __syncthreads(); }
      float bmx = redA[0];
      __syncthreads();
      redA[tid] = (tid < nv) ? expf(lv - bmx) : 0.f;
      __syncthreads();
      for (int off = 256; off > 0; off >>= 1) { if (tid < off) redA[tid] += redA[tid + off]; __syncthreads(); }
      if (tid == 0) { scst(ws + OFF_BM + bid, bmx); scst(ws + OFF_BS + bid, redA[0]); }
    }
    ++ep; gbar(grr, gop, ep, bid, tid);

    // ---- S4: global softmax combine + final write + scatter + argmax partial ----
    {
      if (tid < 256) { redA[tid] = scld(ws + OFF_BM + tid); redB[tid] = scld(ws + OFF_BS + tid); }
      __syncthreads();
      for (int off = 128; off > 0; off >>= 1) {
        if (tid < off) {
          float m1 = redA[tid], m2 = redA[tid + off];
          float mm = fmaxf(m1, m2);
          redB[tid] = redB[tid] * expf(m1 - mm) + redB[tid + off] * expf(m2 - mm);
          redA[tid] = mm;
        }
        __syncthreads();
      }
      float M = redA[0], Sg = redB[0];
      float pc = scalL[0];
      float scale = (1.f - pc) / Sg;
      int v = vbase + tid;
      bool act = (tid < VPB) && (v < VTOT);
      float val = -1e30f;
      if (act) {
        val = (v < VOCAB) ? scale * expf(logitsL[tid] - M) : 0.f;
        int jb = BST[bid], je = BST[bid + 1];
        for (int j = jb; j < je; ++j)
          if (SK[j] == v) val += pc * attnL[SP[j]];
        out[(size_t)t * VTOT + v] = val;
      }
      __syncthreads();
      redA[tid] = act ? val : -1e30f; redI[tid] = v;
      __syncthreads();
      for (int off = 256; off > 0; off >>= 1) {
        if (tid < off) {
          float v2 = redA[tid + off]; int i2 = redI[tid + off];
          if (v2 > redA[tid] || (v2 == redA[tid] && i2 < redI[tid])) { redA[tid] = v2; redI[tid] = i2; }
        }
        __syncthreads();
      }
      if (tid == 0) { scst(ws + OFF_AVAL + bid, redA[0]); scsti(AIX + bid, redI[0]); }
    }
    ++ep; gbar(grr, gop, ep, bid, tid);
  }
}

// ---------------- host ----------------
extern "C" void kernel_launch(void* const* d_in, const int* in_sizes, int n_in,
                              void* d_out, int out_size, void* d_ws, size_t ws_size,
                              hipStream_t stream) {
  const int*   ids  = (const int*)d_in[0];
  const float* embt = (const float*)d_in[1];
  const float* ewf  = (const float*)d_in[2];
  const float* ehf  = (const float*)d_in[3];
  const float* ebif = (const float*)d_in[4];
  const float* ebhf = (const float*)d_in[5];
  const float* ewb  = (const float*)d_in[6];
  const float* ehb  = (const float*)d_in[7];
  const float* ebib = (const float*)d_in[8];
  const float* ebhb = (const float*)d_in[9];
  const float* dwih = (const float*)d_in[10];
  const float* dwhh = (const float*)d_in[11];
  const float* dbih = (const float*)d_in[12];
  const float* dbhh = (const float*)d_in[13];
  const float* eap  = (const float*)d_in[14];
  const float* dap  = (const float*)d_in[15];
  const float* vp   = (const float*)d_in[16];
  const float* ob   = (const float*)d_in[17];
  const float* sw   = (const float*)d_in[18];
  const float* sb   = (const float*)d_in[19];
  float* out = (float*)d_out;
  float* ws  = (float*)d_ws;

  k_setup<<<1592, 256, 0, stream>>>(ws, ids, embt, ewf, ewb, eap);
  k_fused<<<256, 512, 0, stream>>>(ws, out, ids, embt, dwih, dwhh, dbih, dbhh,
                                   dap, ob, sw, sb, ebif, ebhf, ebib, ebhb,
                                   ehf, ehb, vp);
}

// Round 5
// 22117.543 us; speedup vs baseline: 2.0054x; 1.0029x over previous
//
#include <hip/hip_runtime.h>
#include <cstdint>

#define VOCAB 50257
#define VTOT  50321
#define TDEC  100
#define UNK   3
#define VPB   197          // vocab slice per block (197*256=50432 >= 50321)

// ---------------- workspace layout (float offsets) ----------------
static const size_t OFF_EMB    = 0;        // [1024][128]
static const size_t OFF_WIHT_F = 131072;   // [128][640]
static const size_t OFF_WIHT_B = 212992;   // [128][640]
static const size_t OFF_WTE    = 294912;   // [320][320]  enc_attn_proj^T
static const size_t OFF_XG     = 397312;   // [2][1024][640] (prologue only)
static const size_t OFF_CPAR   = 397312;   // [32][320] enc_ctx partials (decode; aliases XG)
static const size_t OFF_ENCH   = 1708032;  // [1024][320]
static const size_t OFF_EPH    = 2035712;  // [1024][320]
static const size_t OFF_SCORES = 2445664;  // 1024
static const size_t OFF_GATES  = 2447328;  // 1280
static const size_t OFF_BM     = 2448608;  // 256
static const size_t OFF_BS     = 2448864;  // 256
static const size_t OFF_AVAL   = 2449120;  // 256
static const size_t OFF_AIDX   = 2449376;  // 256 (int)
static const size_t OFF_H0     = 2449632;  // 320
static const size_t OFF_SKEY   = 2449984;  // 1024 (int)
static const size_t OFF_SPOS   = 2451008;  // 1024 (int)
static const size_t OFF_BSTART = 2452032;  // 257 (int)
static const size_t OFF_WBF16  = 2452352;  // bf16 out_proj, 50257*480 u32
static const size_t OFF_GARR   = 26575712; // u32 idx: 64 lines x 32 u32 (arrivals)
static const size_t OFF_GOPR   = 26577760; // u32 idx: 256 lines x 32 u32 (go words)

__device__ __forceinline__ float sigmf(float x) { return 1.f / (1.f + expf(-x)); }

__device__ __forceinline__ float wsum64(float x) {
#pragma unroll
  for (int m = 1; m < 64; m <<= 1) x += __shfl_xor(x, m, 64);
  return x;
}

__device__ __forceinline__ unsigned short bf16r(float x) {
  uint32_t b = __float_as_uint(x);
  uint32_t r = (b + 0x7fffu + ((b >> 16) & 1u)) >> 16;
  return (unsigned short)r;
}

// agent-scope accesses: coherent across XCDs, bypass stale L1/L2 copies
__device__ __forceinline__ float scld(const float* p) {
  return __hip_atomic_load(p, __ATOMIC_RELAXED, __HIP_MEMORY_SCOPE_AGENT);
}
__device__ __forceinline__ int scldi(const int* p) {
  return __hip_atomic_load(p, __ATOMIC_RELAXED, __HIP_MEMORY_SCOPE_AGENT);
}
__device__ __forceinline__ unsigned scldu(const unsigned* p) {
  return __hip_atomic_load(p, __ATOMIC_RELAXED, __HIP_MEMORY_SCOPE_AGENT);
}
__device__ __forceinline__ void scst(float* p, float v) {
  __hip_atomic_store(p, v, __ATOMIC_RELAXED, __HIP_MEMORY_SCOPE_AGENT);
}
__device__ __forceinline__ void scsti(int* p, int v) {
  __hip_atomic_store(p, v, __ATOMIC_RELAXED, __HIP_MEMORY_SCOPE_AGENT);
}
__device__ __forceinline__ void scstu(unsigned* p, unsigned v) {
  __hip_atomic_store(p, v, __ATOMIC_RELAXED, __HIP_MEMORY_SCOPE_AGENT);
}

__device__ __forceinline__ float fp8dec(unsigned w, int sel) {
  return __builtin_amdgcn_cvt_f32_fp8((int)((w >> (sel * 8)) & 0xffu), 0);
}

// Fan-in/fan-out grid barrier (no hot line, no fences in decode loop)
__device__ __forceinline__ void gbar(unsigned* grr, unsigned* gop, unsigned ep,
                                     int bid, int tid) {
  __syncthreads();  // drains vmcnt: prior sc stores visible at coherence point
  if (tid == 0)
    __hip_atomic_fetch_add(grr + (bid & 63) * 32, 1u, __ATOMIC_RELAXED, __HIP_MEMORY_SCOPE_AGENT);
  if (bid == 0) {
    if (tid < 64) {
      unsigned need = 4u * ep;
      while (scldu(grr + tid * 32) < need) __builtin_amdgcn_s_sleep(4);
    }
    __syncthreads();
    if (tid >= 1 && tid < 256) scstu(gop + tid * 32, ep);
    __syncthreads();
  } else {
    if (tid == 0) {
      while (scldu(gop + bid * 32) < ep) __builtin_amdgcn_s_sleep(4);
    }
    __syncthreads();
  }
}

__device__ __forceinline__ void gbar_full(unsigned* grr, unsigned* gop, unsigned ep,
                                          int bid, int tid) {
  __threadfence();
  gbar(grr, gop, ep, bid, tid);
  __threadfence();
}

// ---------------- setup: embedding gather, weight transposes, barrier reset ----------------
__global__ __launch_bounds__(256) void k_setup(float* __restrict__ ws, const int* __restrict__ ids,
                                               const float* __restrict__ embt, const float* __restrict__ ewf,
                                               const float* __restrict__ ewb, const float* __restrict__ eap) {
  int idx = blockIdx.x * 256 + threadIdx.x;
  if (idx < 131072) {
    int tt = idx >> 7, e = idx & 127;
    int id = ids[tt]; if (id >= VOCAB) id = UNK;
    ws[OFF_EMB + idx] = embt[(size_t)id * 128 + e];
  } else if (idx < 212992) {
    int i = idx - 131072;
    int k = i / 640, g = i - (i / 640) * 640;
    ws[OFF_WIHT_F + i] = ewf[(size_t)g * 128 + k];
  } else if (idx < 294912) {
    int i = idx - 212992;
    int k = i / 640, g = i - (i / 640) * 640;
    ws[OFF_WIHT_B + i] = ewb[(size_t)g * 128 + k];
  } else if (idx < 397312) {
    int i = idx - 294912;
    int k = i / 320, j = i - (i / 320) * 320;
    ws[OFF_WTE + i] = eap[(size_t)j * 320 + k];
  } else if (idx < 407552) {
    ((unsigned*)ws)[OFF_GARR + (idx - 397312)] = 0u;  // GARR + GOPR contiguous
  }
}

// ---------------- fused persistent kernel ----------------
__global__ __launch_bounds__(512, 2) void k_fused(
    float* __restrict__ ws, float* __restrict__ out, const int* __restrict__ ids,
    const float* __restrict__ embt,
    const float* __restrict__ dwih, const float* __restrict__ dwhh,
    const float* __restrict__ dbih, const float* __restrict__ dbhh,
    const float* __restrict__ dap, const float* __restrict__ ob,
    const float* __restrict__ sw, const float* __restrict__ sb,
    const float* __restrict__ ebif, const float* __restrict__ ebhf,
    const float* __restrict__ ebib, const float* __restrict__ ebhb,
    const float* __restrict__ whh_f, const float* __restrict__ whh_b,
    const float* __restrict__ vp) {
  __shared__ float POOL[12352];  // 49.4 KB
  unsigned* decbufU = (unsigned*)POOL;       // [100][80] u32 = fp8 x4 (32 KB)
  float* attnL   = POOL + 8000;   // 1024
  float* concatL = POOL + 9024;   // 960  [h | enc_ctx | dec_ctx]
  float* redA    = POOL + 9984;   // 512
  float* redB    = POOL + 10496;  // 512
  int*   redI    = (int*)(POOL + 11008); // 512
  float* dsL     = POOL + 11520;  // 128
  float* daL     = POOL + 11648;  // 128
  float* logitsL = POOL + 11776;  // 200
  float* hpL     = POOL + 11976;  // 320
  float* scalL   = POOL + 12296;  // 1
  // prologue aliases
  float* As   = POOL;             // 64x129
  float* Bs   = POOL + 8256;      // 64x64
  float* hbuf = POOL;             // 160
  float* part = POOL + 160;       // 4x640

  const int tid = threadIdx.x, bid = blockIdx.x;
  const int l = tid & 63, wv = tid >> 6;
  unsigned* grr = (unsigned*)ws + OFF_GARR;
  unsigned* gop = (unsigned*)ws + OFF_GOPR;
  unsigned ep = 0;

  // ======== Stage A: encoder x-part gates ========
  {
    const int base = bid * 512 + tid;
#pragma unroll
    for (int i = 0; i < 10; ++i) {
      int idx = i * 131072 + base;
      int d = idx / 655360;
      int r = idx - d * 655360;
      int tt = r / 640, g = r - (r / 640) * 640;
      const float* wT = ws + (d ? OFF_WIHT_B : OFF_WIHT_F);
      const float* er = ws + OFF_EMB + (size_t)(d ? (1023 - tt) : tt) * 128;
      float acc = d ? (ebib[g] + ebhb[g]) : (ebif[g] + ebhf[g]);
#pragma unroll 4
      for (int k = 0; k < 128; ++k) acc += er[k] * wT[(size_t)k * 640 + g];
      ws[OFF_XG + idx] = acc;
    }
  }
  ++ep; gbar_full(grr, gop, ep, bid, tid);

  // ======== Stage B: encoder (blocks 0,1) || out_proj GEMM (blocks 2..255) ========
  if (bid < 2) {
    const int dir = bid;
    const float* whh = dir ? whh_b : whh_f;
    const float* xg = ws + OFF_XG + (size_t)dir * 655360;
    const int q = tid & 127, kg = tid >> 7, ks = kg * 40;
    float w[5][40];
#pragma unroll
    for (int j = 0; j < 5; ++j)
#pragma unroll
      for (int i = 0; i < 40; ++i)
        w[j][i] = whh[(size_t)(5 * q + j) * 160 + ks + i];
    float cst = 0.f;
    if (tid < 160) hbuf[tid] = 0.f;
    __syncthreads();
    for (int t = 0; t < 1024; ++t) {
      float acc[5] = {0.f, 0.f, 0.f, 0.f, 0.f};
#pragma unroll
      for (int i4 = 0; i4 < 10; ++i4) {
        float4 h4 = *(const float4*)&hbuf[ks + i4 * 4];
#pragma unroll
        for (int j = 0; j < 5; ++j)
          acc[j] += w[j][i4 * 4 + 0] * h4.x + w[j][i4 * 4 + 1] * h4.y + w[j][i4 * 4 + 2] * h4.z + w[j][i4 * 4 + 3] * h4.w;
      }
#pragma unroll
      for (int j = 0; j < 5; ++j) part[kg * 640 + 5 * q + j] = acc[j];
      __syncthreads();
      if (tid < 160) {
        float gi = xg[(size_t)t * 640 + tid];
        float gf = xg[(size_t)t * 640 + 160 + tid];
        float gg = xg[(size_t)t * 640 + 320 + tid];
        float go = xg[(size_t)t * 640 + 480 + tid];
#pragma unroll
        for (int k2 = 0; k2 < 4; ++k2) {
          gi += part[k2 * 640 + tid]; gf += part[k2 * 640 + 160 + tid];
          gg += part[k2 * 640 + 320 + tid]; go += part[k2 * 640 + 480 + tid];
        }
        cst = sigmf(gf) * cst + sigmf(gi) * tanhf(gg);
        float hn = sigmf(go) * tanhf(cst);
        hbuf[tid] = hn;
        int trow = dir ? (1023 - t) : t;
        ws[OFF_ENCH + (size_t)trow * 320 + dir * 160 + tid] = hn;
      }
      __syncthreads();
    }
    if (tid < 160) ws[OFF_H0 + dir * 160 + tid] = hbuf[tid];
  } else {
    unsigned short* Wo = (unsigned short*)(ws + OFF_WBF16);
    const int mi = tid >> 4, ni = tid & 15;
    for (int tile = bid - 2; tile < 786 * 15; tile += 254) {
      int v0 = (tile % 786) * 64, n0 = (tile / 786) * 64;
      __syncthreads();
#pragma unroll
      for (int c = 0; c < 16; ++c) {
        int idx = c * 512 + tid;
        int m = idx >> 7, k = idx & 127;
        As[m * 129 + k] = (v0 + m < VOCAB) ? embt[(size_t)(v0 + m) * 128 + k] : 0.f;
      }
      float acc[2][4] = {};
      for (int half = 0; half < 2; ++half) {
        __syncthreads();
#pragma unroll
        for (int c = 0; c < 8; ++c) {
          int idx = c * 512 + tid;
          int k = idx >> 6, n = idx & 63;
          Bs[k * 64 + n] = vp[(size_t)(half * 64 + k) * 960 + n0 + n];
        }
        __syncthreads();
        for (int k = 0; k < 64; ++k) {
          float a0 = As[(mi * 2) * 129 + half * 64 + k];
          float a1 = As[(mi * 2 + 1) * 129 + half * 64 + k];
          float4 b = *(const float4*)&Bs[k * 64 + ni * 4];
          acc[0][0] += a0 * b.x; acc[0][1] += a0 * b.y; acc[0][2] += a0 * b.z; acc[0][3] += a0 * b.w;
          acc[1][0] += a1 * b.x; acc[1][1] += a1 * b.y; acc[1][2] += a1 * b.z; acc[1][3] += a1 * b.w;
        }
      }
#pragma unroll
      for (int i = 0; i < 2; ++i) {
        int v = v0 + mi * 2 + i;
        if (v < VOCAB) {
          ushort4 pk;
          pk.x = bf16r(tanhf(acc[i][0])); pk.y = bf16r(tanhf(acc[i][1]));
          pk.z = bf16r(tanhf(acc[i][2])); pk.w = bf16r(tanhf(acc[i][3]));
          *(ushort4*)&Wo[(size_t)v * 960 + n0 + ni * 4] = pk;
        }
      }
    }
  }
  ++ep; gbar_full(grr, gop, ep, bid, tid);

  // ======== Stage C: enc_proj_h + h0 init + id sort (block 0) ========
  if (tid < 320) {
    for (int r = 0; r < 4; ++r) {
      int s = bid * 4 + r;
      const float* er = ws + OFF_ENCH + (size_t)s * 320;
      const float* wt = ws + OFF_WTE;
      float acc = 0.f;
#pragma unroll 4
      for (int k = 0; k < 320; ++k) acc += er[k] * wt[(size_t)k * 320 + tid];
      ws[OFF_EPH + (size_t)s * 320 + tid] = acc;
    }
    concatL[tid] = ws[OFF_H0 + tid];
  }
  __syncthreads();
  if (bid == 0) {
    int* sk = (int*)POOL;
    int* sp = (int*)POOL + 1024;
    for (int j = tid; j < 1024; j += 512) { sk[j] = ids[j]; sp[j] = j; }
    __syncthreads();
    for (int k = 2; k <= 1024; k <<= 1)
      for (int j = k >> 1; j > 0; j >>= 1) {
        for (int i = tid; i < 1024; i += 512) {
          int ixj = i ^ j;
          if (ixj > i) {
            bool up = ((i & k) == 0);
            int a = sk[i], b2 = sk[ixj];
            if (up ? (a > b2) : (a < b2)) {
              sk[i] = b2; sk[ixj] = a;
              int pa = sp[i]; sp[i] = sp[ixj]; sp[ixj] = pa;
            }
          }
        }
        __syncthreads();
      }
    int* BST = (int*)(ws + OFF_BSTART);
    int* SK = (int*)(ws + OFF_SKEY);
    int* SP = (int*)(ws + OFF_SPOS);
    for (int j = tid; j < 1024; j += 512) {
      SK[j] = sk[j]; SP[j] = sp[j];
      int o1 = sk[j] / VPB;
      int o0 = (j == 0) ? -1 : (sk[j - 1] / VPB);
      for (int o = o0 + 1; o <= o1; ++o) BST[o] = j;
    }
    if (tid == 0) {
      int olast = sk[1023] / VPB;
      for (int o = olast + 1; o <= 256; ++o) BST[o] = 1024;
    }
  }
  ++ep; gbar_full(grr, gop, ep, bid, tid);

  // ======== decode loop ========
  const unsigned* W = (const unsigned*)(ws + OFF_WBF16);
  const int* BST = (const int*)(ws + OFF_BSTART);
  const int* SK = (const int*)(ws + OFF_SKEY);
  const int* SP = (const int*)(ws + OFF_SPOS);
  int* AIX = (int*)(ws + OFF_AIDX);
  float creg = 0.f, cum0 = 0.f, cum1 = 0.f;
  const int vbase = bid * VPB;
  const int nv = (VOCAB - vbase < VPB) ? (VOCAB - vbase) : VPB;

  for (int t = 0; t < TDEC; ++t) {
    // ---- S0: token reduce (t>0) + gates ----
    int token = 0;
    if (t > 0) {
      if (tid < 256) { redA[tid] = scld(ws + OFF_AVAL + tid); redI[tid] = scldi(AIX + tid); }
      __syncthreads();
      for (int off = 128; off > 0; off >>= 1) {
        if (tid < off) {
          float v2 = redA[tid + off]; int i2 = redI[tid + off];
          if (v2 > redA[tid] || (v2 == redA[tid] && i2 < redI[tid])) { redA[tid] = v2; redI[tid] = i2; }
        }
        __syncthreads();
      }
      token = redI[0];
      __syncthreads();
    }
    int tokm = (token >= VOCAB) ? UNK : token;
    if (bid < 160) {
      int g = bid * 8 + wv;
      float xv0 = embt[(size_t)tokm * 128 + l];
      float xv1 = embt[(size_t)tokm * 128 + 64 + l];
      float hv[5];
#pragma unroll
      for (int c = 0; c < 5; ++c) hv[c] = concatL[c * 64 + l];
      float acc = dwih[(size_t)g * 128 + l] * xv0 + dwih[(size_t)g * 128 + 64 + l] * xv1;
#pragma unroll
      for (int c = 0; c < 5; ++c) acc += dwhh[(size_t)g * 320 + c * 64 + l] * hv[c];
      acc = wsum64(acc);
      if (l == 0) scst(ws + OFF_GATES + g, acc + dbih[g] + dbhh[g]);
    }
    ++ep; gbar(grr, gop, ep, bid, tid);

    // ---- S1: h,c update (redundant) + fp8 decbuf + hp (block-local) + scores ----
    if (tid < 320) {
      float gi = scld(ws + OFF_GATES + tid);
      float gf = scld(ws + OFF_GATES + 320 + tid);
      float gg = scld(ws + OFF_GATES + 640 + tid);
      float go = scld(ws + OFF_GATES + 960 + tid);
      creg = sigmf(gf) * creg + sigmf(gi) * tanhf(gg);
      concatL[tid] = sigmf(go) * tanhf(creg);
    }
    __syncthreads();
    if (tid < 80) {
      int lo = __builtin_amdgcn_cvt_pk_fp8_f32(concatL[4 * tid], concatL[4 * tid + 1], 0, false);
      int both = __builtin_amdgcn_cvt_pk_fp8_f32(concatL[4 * tid + 2], concatL[4 * tid + 3], lo, true);
      decbufU[t * 80 + tid] = (unsigned)both;
    }
    if (bid < 128) {
      int g = bid * 8 + wv;
      const float* er = ws + OFF_EPH + (size_t)g * 320;
      float acc = 0.f;
#pragma unroll
      for (int c = 0; c < 5; ++c) acc += er[c * 64 + l] * concatL[c * 64 + l];
      acc = wsum64(acc);
      if (l == 0) scst(ws + OFF_SCORES + g, acc);
    }
    // hp = h @ dec_attn_proj, computed redundantly per block (no atomics)
    if (tid < 320) {
      float acc = 0.f;
#pragma unroll 8
      for (int i = 0; i < 320; ++i) acc += concatL[i] * dap[(size_t)i * 320 + tid];
      hpL[tid] = acc;
    }
    ++ep; gbar(grr, gop, ep, bid, tid);

    // ---- S2: temporal softmax + enc_ctx partials (distinct slices) + dec attention ----
    {
      float s0 = scld(ws + OFF_SCORES + tid);
      float s1 = scld(ws + OFF_SCORES + 512 + tid);
      float t0 = (t == 0) ? s0 : expf(s0) / cum0;
      float t1 = (t == 0) ? s1 : expf(s1) / cum1;
      cum0 += s0; cum1 += s1;
      redA[tid] = fmaxf(t0, t1);
      __syncthreads();
      for (int off = 256; off > 0; off >>= 1) { if (tid < off) redA[tid] = fmaxf(redA[tid], redA[tid + off]); __syncthreads(); }
      float mx = redA[0];
      __syncthreads();
      redA[tid] = expf(t0 - mx) + expf(t1 - mx);
      __syncthreads();
      for (int off = 256; off > 0; off >>= 1) { if (tid < off) redA[tid] += redA[tid + off]; __syncthreads(); }
      float Ssm = redA[0];
      __syncthreads();
      attnL[tid] = expf(t0 - mx) / Ssm;
      attnL[512 + tid] = expf(t1 - mx) / Ssm;
      __syncthreads();  // attnL ready
      if (bid < 32 && tid < 320) {
        float acc = 0.f;
        const float* eh = ws + OFF_ENCH + (size_t)(bid * 32) * 320 + tid;
#pragma unroll 4
        for (int k2 = 0; k2 < 32; ++k2) acc += attnL[bid * 32 + k2] * eh[(size_t)k2 * 320];
        scst(ws + OFF_CPAR + bid * 320 + tid, acc);  // distinct lines, no RMW
      }
      float hpv[5];
#pragma unroll
      for (int c = 0; c < 5; ++c) hpv[c] = hpL[c * 64 + l];
#pragma unroll
      for (int k2 = 0; k2 < 13; ++k2) {
        int tp = wv + 8 * k2;
        if (tp < t) {
          float acc = 0.f;
#pragma unroll
          for (int c = 0; c < 5; ++c)
            acc += hpv[c] * fp8dec(decbufU[tp * 80 + c * 16 + (l >> 2)], l & 3);
          acc = wsum64(acc);
          if (l == 0) dsL[tp] = acc;
        }
      }
      __syncthreads();
      float dv = -1e30f;
      if (tid < 128) { dv = (tid < t) ? dsL[tid] : -1e30f; redA[tid] = dv; }
      __syncthreads();
      for (int off = 64; off > 0; off >>= 1) { if (tid < off) redA[tid] = fmaxf(redA[tid], redA[tid + off]); __syncthreads(); }
      float dmx = redA[0];
      __syncthreads();
      float de = (tid < 128) ? expf(dv - dmx) : 0.f;
      if (tid < 128) redA[tid] = de;
      __syncthreads();
      for (int off = 64; off > 0; off >>= 1) { if (tid < off) redA[tid] += redA[tid + off]; __syncthreads(); }
      float dS = redA[0];
      __syncthreads();
      if (tid < 128) daL[tid] = de / dS;
      __syncthreads();
      if (tid < 320) {
        float acc = 0.f;
        for (int tp = 0; tp < t; ++tp)
          acc += daL[tp] * fp8dec(decbufU[tp * 80 + (tid >> 2)], tid & 3);
        concatL[640 + tid] = acc;
      }
    }
    ++ep; gbar(grr, gop, ep, bid, tid);

    // ---- S3: reduce enc_ctx partials + p_copy (redundant) + block logits slice ----
    if (tid < 320) {
      float a = 0.f;
#pragma unroll
      for (int p = 0; p < 32; ++p) a += scld(ws + OFF_CPAR + p * 320 + tid);
      concatL[320 + tid] = a;
    }
    __syncthreads();
    if (tid < 64) {
      float acc = 0.f;
#pragma unroll
      for (int c = 0; c < 15; ++c) acc += sw[c * 64 + l] * concatL[c * 64 + l];
      acc = wsum64(acc);
      if (l == 0) scalL[0] = 1.f / (1.f + expf(-(acc + sb[0])));
    }
    {
      const float2* cL2 = (const float2*)concatL;
      float cc0[7], cc1[7], ct0 = 0.f, ct1 = 0.f;
#pragma unroll
      for (int c = 0; c < 7; ++c) { float2 x = cL2[c * 64 + l]; cc0[c] = x.x; cc1[c] = x.y; }
      if (l < 32) { ct0 = concatL[896 + 2 * l]; ct1 = concatL[897 + 2 * l]; }
      const int rend = (wv * 25 + 25 < 197) ? (wv * 25 + 25) : 197;
      for (int r = wv * 25; r < rend; ++r) {
        int v = vbase + r;
        if (v < VOCAB) {
          const unsigned* row = W + (size_t)v * 480;
          float acc = 0.f;
#pragma unroll
          for (int c = 0; c < 7; ++c) {
            unsigned u = row[c * 64 + l];
            acc += __uint_as_float(u << 16) * cc0[c] + __uint_as_float(u & 0xffff0000u) * cc1[c];
          }
          if (l < 32) {
            unsigned u = row[448 + l];
            acc += __uint_as_float(u << 16) * ct0 + __uint_as_float(u & 0xffff0000u) * ct1;
          }
          acc = wsum64(acc);
          if (l == 0) logitsL[r] = acc + ob[v];
        }
      }
      __syncthreads();
      float lv = (tid < nv) ? logitsL[tid] : -1e30f;
      redA[tid] = lv;
      __syncthreads();
      for (int off = 256; off > 0; off >>= 1) { if (tid < off) redA[tid] = fmaxf(redA[tid], redA[tid + off]); __syncthreads(); }
      float bmx = redA[0];
      __syncthreads();
      redA[tid] = (tid < nv) ? expf(lv - bmx) : 0.f;
      __syncthreads();
      for (int off = 256; off > 0; off >>= 1) { if (tid < off) redA[tid] += redA[tid + off]; __syncthreads(); }
      if (tid == 0) { scst(ws + OFF_BM + bid, bmx); scst(ws + OFF_BS + bid, redA[0]); }
    }
    ++ep; gbar(grr, gop, ep, bid, tid);

    // ---- S4: global softmax combine + final write + scatter + argmax partial ----
    {
      if (tid < 256) { redA[tid] = scld(ws + OFF_BM + tid); redB[tid] = scld(ws + OFF_BS + tid); }
      __syncthreads();
      for (int off = 128; off > 0; off >>= 1) {
        if (tid < off) {
          float m1 = redA[tid], m2 = redA[tid + off];
          float mm = fmaxf(m1, m2);
          redB[tid] = redB[tid] * expf(m1 - mm) + redB[tid + off] * expf(m2 - mm);
          redA[tid] = mm;
        }
        __syncthreads();
      }
      float M = redA[0], Sg = redB[0];
      float pc = scalL[0];
      float scale = (1.f - pc) / Sg;
      int v = vbase + tid;
      bool act = (tid < VPB) && (v < VTOT);
      float val = -1e30f;
      if (act) {
        val = (v < VOCAB) ? scale * expf(logitsL[tid] - M) : 0.f;
        int jb = BST[bid], je = BST[bid + 1];
        for (int j = jb; j < je; ++j)
          if (SK[j] == v) val += pc * attnL[SP[j]];
        out[(size_t)t * VTOT + v] = val;
      }
      __syncthreads();
      redA[tid] = act ? val : -1e30f; redI[tid] = v;
      __syncthreads();
      for (int off = 256; off > 0; off >>= 1) {
        if (tid < off) {
          float v2 = redA[tid + off]; int i2 = redI[tid + off];
          if (v2 > redA[tid] || (v2 == redA[tid] && i2 < redI[tid])) { redA[tid] = v2; redI[tid] = i2; }
        }
        __syncthreads();
      }
      if (tid == 0) { scst(ws + OFF_AVAL + bid, redA[0]); scsti(AIX + bid, redI[0]); }
    }
    ++ep; gbar(grr, gop, ep, bid, tid);
  }
}

// ---------------- host ----------------
extern "C" void kernel_launch(void* const* d_in, const int* in_sizes, int n_in,
                              void* d_out, int out_size, void* d_ws, size_t ws_size,
                              hipStream_t stream) {
  const int*   ids  = (const int*)d_in[0];
  const float* embt = (const float*)d_in[1];
  const float* ewf  = (const float*)d_in[2];
  const float* ehf  = (const float*)d_in[3];
  const float* ebif = (const float*)d_in[4];
  const float* ebhf = (const float*)d_in[5];
  const float* ewb  = (const float*)d_in[6];
  const float* ehb  = (const float*)d_in[7];
  const float* ebib = (const float*)d_in[8];
  const float* ebhb = (const float*)d_in[9];
  const float* dwih = (const float*)d_in[10];
  const float* dwhh = (const float*)d_in[11];
  const float* dbih = (const float*)d_in[12];
  const float* dbhh = (const float*)d_in[13];
  const float* eap  = (const float*)d_in[14];
  const float* dap  = (const float*)d_in[15];
  const float* vp   = (const float*)d_in[16];
  const float* ob   = (const float*)d_in[17];
  const float* sw   = (const float*)d_in[18];
  const float* sb   = (const float*)d_in[19];
  float* out = (float*)d_out;
  float* ws  = (float*)d_ws;

  k_setup<<<1592, 256, 0, stream>>>(ws, ids, embt, ewf, ewb, eap);
  k_fused<<<256, 512, 0, stream>>>(ws, out, ids, embt, dwih, dwhh, dbih, dbhh,
                                   dap, ob, sw, sb, ebif, ebhf, ebib, ebhb,
                                   ehf, ehb, vp);
}

// Round 6
// 7843.924 us; speedup vs baseline: 5.6546x; 2.8197x over previous
//
#include <hip/hip_runtime.h>
#include <cstdint>

#define VOCAB 50257
#define VTOT  50321
#define TDEC  100
#define UNK   3
#define VPB   99           // vocab rows per block in logits/final (512*99=50688>=50321)

// ---------------- workspace layout (float offsets) ----------------
static const size_t OFF_EMB    = 0;        // [1024][128]
static const size_t OFF_WIHT_F = 131072;   // [128][640]
static const size_t OFF_WIHT_B = 212992;   // [128][640]
static const size_t OFF_WTE    = 294912;   // [320][320]
static const size_t OFF_XG     = 397312;   // [2][1024][640]
static const size_t OFF_ENCH   = 1708032;  // [1024][320]
static const size_t OFF_EPH    = 2035712;  // [1024][320]
static const size_t OFF_DECBUF = 2363392;  // [100][320]
static const size_t OFF_LOGITS = 2395392;  // 50688
static const size_t OFF_SCORES = 2446080;  // 1024
static const size_t OFF_GATES  = 2447104;  // 1280
static const size_t OFF_HPAR   = 2448384;  // [8][320]
static const size_t OFF_CPAR   = 2450944;  // [16][320]
static const size_t OFF_DCTX   = 2456064;  // 320
static const size_t OFF_H      = 2456384;  // 320
static const size_t OFF_H0     = 2456704;  // 320
static const size_t OFF_CA     = 2457024;  // 320
static const size_t OFF_CB     = 2457344;  // 320
static const size_t OFF_CUMA   = 2457664;  // 1024
static const size_t OFF_CUMB   = 2458688;  // 1024
static const size_t OFF_ATTN   = 2459712;  // 1024
static const size_t OFF_BM     = 2460736;  // 512
static const size_t OFF_BS     = 2461248;  // 512
static const size_t OFF_AVAL   = 2461760;  // 512
static const size_t OFF_AIDX   = 2462272;  // 512 (int)
static const size_t OFF_SCAL   = 2462784;  // 1
static const size_t OFF_SKEY   = 2462848;  // 1024 (int)
static const size_t OFF_SPOS   = 2463872;  // 1024 (int)
static const size_t OFF_BSTART = 2464896;  // 513 (int)
static const size_t OFF_WBF16  = 2465792;  // bf16 out_proj, 50257*480 u32

__device__ __forceinline__ float sigmf(float x) { return 1.f / (1.f + expf(-x)); }

__device__ __forceinline__ float wsum64(float x) {
#pragma unroll
  for (int m = 1; m < 64; m <<= 1) x += __shfl_xor(x, m, 64);
  return x;
}

__device__ __forceinline__ unsigned short bf16r(float x) {
  uint32_t b = __float_as_uint(x);
  uint32_t r = (b + 0x7fffu + ((b >> 16) & 1u)) >> 16;
  return (unsigned short)r;
}

// ---------------- P1: gather embeddings, transposes, state zero-init ----------------
__global__ __launch_bounds__(256) void k_setup(float* __restrict__ ws, const int* __restrict__ ids,
                                               const float* __restrict__ embt, const float* __restrict__ ewf,
                                               const float* __restrict__ ewb, const float* __restrict__ eap) {
  int idx = blockIdx.x * 256 + threadIdx.x;
  if (idx < 131072) {
    int tt = idx >> 7, e = idx & 127;
    int id = ids[tt]; if (id >= VOCAB) id = UNK;
    ws[OFF_EMB + idx] = embt[(size_t)id * 128 + e];
  } else if (idx < 212992) {
    int i = idx - 131072;
    int k = i / 640, g = i - (i / 640) * 640;
    ws[OFF_WIHT_F + i] = ewf[(size_t)g * 128 + k];
  } else if (idx < 294912) {
    int i = idx - 212992;
    int k = i / 640, g = i - (i / 640) * 640;
    ws[OFF_WIHT_B + i] = ewb[(size_t)g * 128 + k];
  } else if (idx < 397312) {
    int i = idx - 294912;
    int k = i / 320, j = i - (i / 320) * 320;
    ws[OFF_WTE + i] = eap[(size_t)j * 320 + k];
  } else if (idx < 398656) {
    int i = idx - 397312;
    if (i < 320) ws[OFF_CA + i] = 0.f;
    else         ws[OFF_CUMA + (i - 320)] = 0.f;
  }
}

// ---------------- P2: encoder x-part gates ----------------
__global__ __launch_bounds__(256) void k_xg(float* __restrict__ ws,
                                            const float* __restrict__ bif, const float* __restrict__ bhf,
                                            const float* __restrict__ bib, const float* __restrict__ bhb) {
  int idx = blockIdx.x * 256 + threadIdx.x;
  int d = idx / 655360;
  int r = idx - d * 655360;
  int tt = r / 640, g = r - (r / 640) * 640;
  const float* wT = ws + (d ? OFF_WIHT_B : OFF_WIHT_F);
  const float* er = ws + OFF_EMB + (size_t)(d ? (1023 - tt) : tt) * 128;
  float acc = d ? (bib[g] + bhb[g]) : (bif[g] + bhf[g]);
#pragma unroll 4
  for (int k = 0; k < 128; ++k) acc += er[k] * wT[(size_t)k * 640 + g];
  ws[OFF_XG + idx] = acc;
}

// ---------------- P3: out_proj = bf16(tanh(embedding @ vocab_proj)) ----------------
__global__ __launch_bounds__(256) void k_outproj(const float* __restrict__ embt, const float* __restrict__ vp,
                                                 float* __restrict__ ws) {
  __shared__ float As[64][128];
  __shared__ float Bs[128][64];
  const int tid = threadIdx.x;
  const int v0 = blockIdx.x * 64, n0 = blockIdx.y * 64;
  for (int c = 0; c < 32; ++c) {
    int idx = c * 256 + tid;
    int m = idx >> 7, k = idx & 127;
    int v = v0 + m;
    As[m][k] = (v < VOCAB) ? embt[(size_t)v * 128 + k] : 0.f;
    int k2 = idx >> 6, n = idx & 63;
    Bs[k2][n] = vp[(size_t)k2 * 960 + n0 + n];
  }
  __syncthreads();
  const int mi = tid >> 4, ni = tid & 15;
  float acc[4][4] = {};
  for (int k = 0; k < 128; ++k) {
    float a0 = As[mi * 4 + 0][k], a1 = As[mi * 4 + 1][k], a2 = As[mi * 4 + 2][k], a3 = As[mi * 4 + 3][k];
    float4 b = *(const float4*)&Bs[k][ni * 4];
    acc[0][0] += a0 * b.x; acc[0][1] += a0 * b.y; acc[0][2] += a0 * b.z; acc[0][3] += a0 * b.w;
    acc[1][0] += a1 * b.x; acc[1][1] += a1 * b.y; acc[1][2] += a1 * b.z; acc[1][3] += a1 * b.w;
    acc[2][0] += a2 * b.x; acc[2][1] += a2 * b.y; acc[2][2] += a2 * b.z; acc[2][3] += a2 * b.w;
    acc[3][0] += a3 * b.x; acc[3][1] += a3 * b.y; acc[3][2] += a3 * b.z; acc[3][3] += a3 * b.w;
  }
  unsigned short* W = (unsigned short*)(ws + OFF_WBF16);
#pragma unroll
  for (int i = 0; i < 4; ++i) {
    int v = v0 + mi * 4 + i;
    if (v < VOCAB) {
      ushort4 pk;
      pk.x = bf16r(tanhf(acc[i][0]));
      pk.y = bf16r(tanhf(acc[i][1]));
      pk.z = bf16r(tanhf(acc[i][2]));
      pk.w = bf16r(tanhf(acc[i][3]));
      *(ushort4*)&W[(size_t)v * 960 + n0 + ni * 4] = pk;
    }
  }
}

// ---------------- P4: sequential bi-LSTM encoder ----------------
__global__ __launch_bounds__(512) void k_encoder(float* __restrict__ ws, const float* __restrict__ whh_f,
                                                 const float* __restrict__ whh_b) {
  const int dir = blockIdx.x;
  const int tid = threadIdx.x;
  const float* whh = dir ? whh_b : whh_f;
  const float* xg = ws + OFF_XG + (size_t)dir * 655360;
  __shared__ float hbuf[160];
  __shared__ float part[4][640];
  const int q = tid & 127, kg = tid >> 7, ks = kg * 40;
  float w[5][40];
#pragma unroll
  for (int j = 0; j < 5; ++j)
#pragma unroll
    for (int i = 0; i < 40; ++i)
      w[j][i] = whh[(size_t)(5 * q + j) * 160 + ks + i];
  float cst = 0.f;
  if (tid < 160) hbuf[tid] = 0.f;
  __syncthreads();
  for (int t = 0; t < 1024; ++t) {
    float acc[5] = {0.f, 0.f, 0.f, 0.f, 0.f};
#pragma unroll
    for (int i4 = 0; i4 < 10; ++i4) {
      float4 h4 = *(const float4*)&hbuf[ks + i4 * 4];
#pragma unroll
      for (int j = 0; j < 5; ++j)
        acc[j] += w[j][i4 * 4 + 0] * h4.x + w[j][i4 * 4 + 1] * h4.y + w[j][i4 * 4 + 2] * h4.z + w[j][i4 * 4 + 3] * h4.w;
    }
#pragma unroll
    for (int j = 0; j < 5; ++j) part[kg][5 * q + j] = acc[j];
    __syncthreads();
    if (tid < 160) {
      float gi = xg[(size_t)t * 640 + tid];
      float gf = xg[(size_t)t * 640 + 160 + tid];
      float gg = xg[(size_t)t * 640 + 320 + tid];
      float go = xg[(size_t)t * 640 + 480 + tid];
#pragma unroll
      for (int k2 = 0; k2 < 4; ++k2) {
        gi += part[k2][tid]; gf += part[k2][160 + tid];
        gg += part[k2][320 + tid]; go += part[k2][480 + tid];
      }
      cst = sigmf(gf) * cst + sigmf(gi) * tanhf(gg);
      float hn = sigmf(go) * tanhf(cst);
      hbuf[tid] = hn;
      int trow = dir ? (1023 - t) : t;
      ws[OFF_ENCH + (size_t)trow * 320 + dir * 160 + tid] = hn;
    }
    __syncthreads();
  }
  if (tid < 160) ws[OFF_H0 + dir * 160 + tid] = hbuf[tid];
}

// ---------------- P5: enc_proj_h ----------------
__global__ __launch_bounds__(256) void k_encproj(float* __restrict__ ws) {
  int idx = blockIdx.x * 256 + threadIdx.x;
  int s = idx / 320, j = idx - (idx / 320) * 320;
  const float* er = ws + OFF_ENCH + (size_t)s * 320;
  const float* wt = ws + OFF_WTE;
  float acc = 0.f;
#pragma unroll 4
  for (int k = 0; k < 320; ++k) acc += er[k] * wt[(size_t)k * 320 + j];
  ws[OFF_EPH + idx] = acc;
}

// ---------------- P6: sort ids + slice table + H init ----------------
__global__ __launch_bounds__(512) void k_sort(float* __restrict__ ws, const int* __restrict__ ids) {
  __shared__ int sk[1024], sp[1024];
  const int tid = threadIdx.x;
  for (int j = tid; j < 1024; j += 512) { sk[j] = ids[j]; sp[j] = j; }
  if (tid < 320) ws[OFF_H + tid] = ws[OFF_H0 + tid];
  __syncthreads();
  for (int k = 2; k <= 1024; k <<= 1)
    for (int j = k >> 1; j > 0; j >>= 1) {
      for (int i = tid; i < 1024; i += 512) {
        int ixj = i ^ j;
        if (ixj > i) {
          bool up = ((i & k) == 0);
          int a = sk[i], b2 = sk[ixj];
          if (up ? (a > b2) : (a < b2)) {
            sk[i] = b2; sk[ixj] = a;
            int pa = sp[i]; sp[i] = sp[ixj]; sp[ixj] = pa;
          }
        }
      }
      __syncthreads();
    }
  int* BST = (int*)(ws + OFF_BSTART);
  int* SK = (int*)(ws + OFF_SKEY);
  int* SP = (int*)(ws + OFF_SPOS);
  for (int j = tid; j < 1024; j += 512) {
    SK[j] = sk[j]; SP[j] = sp[j];
    int o1 = sk[j] / VPB;
    int o0 = (j == 0) ? -1 : (sk[j - 1] / VPB);
    for (int o = o0 + 1; o <= o1; ++o) BST[o] = j;
  }
  if (tid == 0) {
    int olast = sk[1023] / VPB;
    for (int o = olast + 1; o <= 512; ++o) BST[o] = 1024;
  }
}

// ---------------- D1: token argmax reduce + decoder gates ----------------
__global__ __launch_bounds__(256) void k_d1_gates(float* __restrict__ ws, const float* __restrict__ embt,
                                                  const float* __restrict__ dwih, const float* __restrict__ dwhh,
                                                  const float* __restrict__ dbih, const float* __restrict__ dbhh,
                                                  int t) {
  __shared__ float rv[256];
  __shared__ int ri[256];
  const int tid = threadIdx.x, bid = blockIdx.x;
  int token = 0;
  if (t > 0) {
    float v0 = ws[OFF_AVAL + tid], v1 = ws[OFF_AVAL + 256 + tid];
    int i0 = ((const int*)(ws + OFF_AIDX))[tid], i1 = ((const int*)(ws + OFF_AIDX))[256 + tid];
    if (v1 > v0 || (v1 == v0 && i1 < i0)) { v0 = v1; i0 = i1; }
    rv[tid] = v0; ri[tid] = i0;
    __syncthreads();
    for (int off = 128; off > 0; off >>= 1) {
      if (tid < off) {
        float b = rv[tid + off]; int bi = ri[tid + off];
        if (b > rv[tid] || (b == rv[tid] && bi < ri[tid])) { rv[tid] = b; ri[tid] = bi; }
      }
      __syncthreads();
    }
    token = ri[0];
  }
  int tokm = (token >= VOCAB) ? UNK : token;
  const int l = tid & 63, wv = tid >> 6;
  float xv0 = embt[(size_t)tokm * 128 + l];
  float xv1 = embt[(size_t)tokm * 128 + 64 + l];
  float hv[5];
#pragma unroll
  for (int c = 0; c < 5; ++c) hv[c] = ws[OFF_H + c * 64 + l];
  const int wg = bid * 4 + wv;
  for (int i = 0; i < 16; ++i) {
    const int r = wg * 16 + i;
    float acc = dwih[(size_t)r * 128 + l] * xv0 + dwih[(size_t)r * 128 + 64 + l] * xv1;
#pragma unroll
    for (int c = 0; c < 5; ++c) acc += dwhh[(size_t)r * 320 + c * 64 + l] * hv[c];
    acc = wsum64(acc);
    if (l == 0) ws[OFF_GATES + r] = acc + dbih[r] + dbhh[r];
  }
}

// ---------------- D2: h,c update (redundant) + scores + hp partials + decbuf ----------------
__global__ __launch_bounds__(512) void k_d2_hs(float* __restrict__ ws, const float* __restrict__ dap, int t) {
  __shared__ float hL[320];
  const int tid = threadIdx.x, bid = blockIdx.x;
  const int par = t & 1;
  const float* cin = ws + (par ? OFF_CB : OFF_CA);
  float* cout = ws + (par ? OFF_CA : OFF_CB);
  if (tid < 320) {
    float gi = ws[OFF_GATES + tid];
    float gf = ws[OFF_GATES + 320 + tid];
    float gg = ws[OFF_GATES + 640 + tid];
    float go = ws[OFF_GATES + 960 + tid];
    float c = sigmf(gf) * cin[tid] + sigmf(gi) * tanhf(gg);
    float hn = sigmf(go) * tanhf(c);
    hL[tid] = hn;
    if (bid == 0) {
      cout[tid] = c;
      ws[OFF_H + tid] = hn;
      ws[OFF_DECBUF + (size_t)t * 320 + tid] = hn;
    }
  }
  __syncthreads();
  if (bid < 32) {
    const int l = tid & 63, wv = tid >> 6;
    float hv[5];
#pragma unroll
    for (int c = 0; c < 5; ++c) hv[c] = hL[c * 64 + l];
#pragma unroll
    for (int i = 0; i < 4; ++i) {
      int s = bid * 32 + wv * 4 + i;
      const float* er = ws + OFF_EPH + (size_t)s * 320;
      float acc = 0.f;
#pragma unroll
      for (int c = 0; c < 5; ++c) acc += er[c * 64 + l] * hv[c];
      acc = wsum64(acc);
      if (l == 0) ws[OFF_SCORES + s] = acc;
    }
  } else if (tid < 320) {
    int q = bid - 32;
    float acc = 0.f;
#pragma unroll 8
    for (int ii = 0; ii < 40; ++ii) {
      int i = q * 40 + ii;
      acc += hL[i] * dap[(size_t)i * 320 + tid];
    }
    ws[OFF_HPAR + q * 320 + tid] = acc;
  }
}

// ---------------- D3: temporal softmax + enc_ctx partials (0..15) | cum + dec attention (16) ----------------
__global__ __launch_bounds__(512) void k_d3_attn(float* __restrict__ ws, int t) {
  __shared__ float attnL[1024];
  __shared__ float redA[512];
  __shared__ float dsL[128];
  __shared__ float daL[128];
  __shared__ float hpL[320];
  const int tid = threadIdx.x, bid = blockIdx.x;
  const int par = t & 1;
  const float* cumin = ws + (par ? OFF_CUMB : OFF_CUMA);
  float* cumout = ws + (par ? OFF_CUMA : OFF_CUMB);

  if (bid < 16) {
    float s0 = ws[OFF_SCORES + tid];
    float s1 = ws[OFF_SCORES + 512 + tid];
    float t0 = (t == 0) ? s0 : expf(s0) / cumin[tid];
    float t1 = (t == 0) ? s1 : expf(s1) / cumin[512 + tid];
    redA[tid] = fmaxf(t0, t1);
    __syncthreads();
    for (int off = 256; off > 0; off >>= 1) { if (tid < off) redA[tid] = fmaxf(redA[tid], redA[tid + off]); __syncthreads(); }
    float mx = redA[0];
    __syncthreads();
    redA[tid] = expf(t0 - mx) + expf(t1 - mx);
    __syncthreads();
    for (int off = 256; off > 0; off >>= 1) { if (tid < off) redA[tid] += redA[tid + off]; __syncthreads(); }
    float Ssm = redA[0];
    __syncthreads();
    attnL[tid] = expf(t0 - mx) / Ssm;
    attnL[512 + tid] = expf(t1 - mx) / Ssm;
    __syncthreads();
    if (tid < 64) ws[OFF_ATTN + bid * 64 + tid] = attnL[bid * 64 + tid];
    if (tid < 320) {
      float acc = 0.f;
      const float* eh = ws + OFF_ENCH + (size_t)(bid * 64) * 320 + tid;
#pragma unroll 4
      for (int k2 = 0; k2 < 64; ++k2) acc += attnL[bid * 64 + k2] * eh[(size_t)k2 * 320];
      ws[OFF_CPAR + bid * 320 + tid] = acc;
    }
  } else {
    cumout[tid] = cumin[tid] + ws[OFF_SCORES + tid];
    cumout[512 + tid] = cumin[512 + tid] + ws[OFF_SCORES + 512 + tid];
    if (tid < 320) {
      float a = 0.f;
#pragma unroll
      for (int q = 0; q < 8; ++q) a += ws[OFF_HPAR + q * 320 + tid];
      hpL[tid] = a;
    }
    __syncthreads();
    const int l = tid & 63, wv = tid >> 6;
    float hpv[5];
#pragma unroll
    for (int c = 0; c < 5; ++c) hpv[c] = hpL[c * 64 + l];
#pragma unroll
    for (int k2 = 0; k2 < 13; ++k2) {
      int tp = wv + 8 * k2;
      if (tp < t) {
        float acc = 0.f;
#pragma unroll
        for (int c = 0; c < 5; ++c) acc += hpv[c] * ws[OFF_DECBUF + (size_t)tp * 320 + c * 64 + l];
        acc = wsum64(acc);
        if (l == 0) dsL[tp] = acc;
      }
    }
    __syncthreads();
    float dv = -1e30f;
    if (tid < 128) { dv = (tid < t) ? dsL[tid] : -1e30f; redA[tid] = dv; }
    __syncthreads();
    for (int off = 64; off > 0; off >>= 1) { if (tid < off) redA[tid] = fmaxf(redA[tid], redA[tid + off]); __syncthreads(); }
    float dmx = redA[0];
    __syncthreads();
    float de = (tid < 128) ? expf(dv - dmx) : 0.f;
    if (tid < 128) redA[tid] = de;
    __syncthreads();
    for (int off = 64; off > 0; off >>= 1) { if (tid < off) redA[tid] += redA[tid + off]; __syncthreads(); }
    float dS = redA[0];
    __syncthreads();
    if (tid < 128) daL[tid] = de / dS;
    __syncthreads();
    if (tid < 320) {
      float acc = 0.f;
      for (int tp = 0; tp < t; ++tp) acc += daL[tp] * ws[OFF_DECBUF + (size_t)tp * 320 + tid];
      ws[OFF_DCTX + tid] = acc;
    }
  }
}

// ---------------- D4: concat assembly + p_copy + logits slice + block softmax partial ----------------
__global__ __launch_bounds__(256) void k_d4_logits(float* __restrict__ ws, const float* __restrict__ ob,
                                                   const float* __restrict__ sw, const float* __restrict__ sb) {
  __shared__ float concatL[960];
  __shared__ float logitsL[128];
  __shared__ float rm[256], rs[256];
  const int tid = threadIdx.x, bid = blockIdx.x;
  for (int i = tid; i < 960; i += 256) {
    float v;
    if (i < 320) v = ws[OFF_H + i];
    else if (i < 640) {
      int j = i - 320;
      float a = 0.f;
#pragma unroll
      for (int p = 0; p < 16; ++p) a += ws[OFF_CPAR + p * 320 + j];
      v = a;
    } else v = ws[OFF_DCTX + (i - 640)];
    concatL[i] = v;
  }
  __syncthreads();
  const int l = tid & 63, wv = tid >> 6;
  if (bid == 0 && tid < 64) {
    float acc = 0.f;
#pragma unroll
    for (int c = 0; c < 15; ++c) acc += sw[c * 64 + l] * concatL[c * 64 + l];
    acc = wsum64(acc);
    if (l == 0) ws[OFF_SCAL] = 1.f / (1.f + expf(-(acc + sb[0])));
  }
  const unsigned* W = (const unsigned*)(ws + OFF_WBF16);
  const float2* cL2 = (const float2*)concatL;
  float cc0[7], cc1[7], ct0 = 0.f, ct1 = 0.f;
#pragma unroll
  for (int c = 0; c < 7; ++c) { float2 x = cL2[c * 64 + l]; cc0[c] = x.x; cc1[c] = x.y; }
  if (l < 32) { ct0 = concatL[896 + 2 * l]; ct1 = concatL[897 + 2 * l]; }
  const int vbase = bid * VPB;
  const int r0 = wv * 25, r1 = (wv * 25 + 25 < VPB) ? (wv * 25 + 25) : VPB;
  for (int r = r0; r < r1; r += 2) {
    int va = vbase + r, vb = va + 1;
    bool oka = (va < VOCAB);
    bool okb = (r + 1 < r1) && (vb < VOCAB);
    float acc0 = 0.f, acc1 = 0.f;
    const unsigned* rowa = W + (size_t)va * 480;
    const unsigned* rowb = W + (size_t)vb * 480;
    unsigned ua[7], ub[7], ta = 0, tb = 0;
    if (oka) {
#pragma unroll
      for (int c = 0; c < 7; ++c) ua[c] = rowa[c * 64 + l];
      if (l < 32) ta = rowa[448 + l];
    }
    if (okb) {
#pragma unroll
      for (int c = 0; c < 7; ++c) ub[c] = rowb[c * 64 + l];
      if (l < 32) tb = rowb[448 + l];
    }
    if (oka) {
#pragma unroll
      for (int c = 0; c < 7; ++c)
        acc0 += __uint_as_float(ua[c] << 16) * cc0[c] + __uint_as_float(ua[c] & 0xffff0000u) * cc1[c];
      if (l < 32) acc0 += __uint_as_float(ta << 16) * ct0 + __uint_as_float(ta & 0xffff0000u) * ct1;
    }
    if (okb) {
#pragma unroll
      for (int c = 0; c < 7; ++c)
        acc1 += __uint_as_float(ub[c] << 16) * cc0[c] + __uint_as_float(ub[c] & 0xffff0000u) * cc1[c];
      if (l < 32) acc1 += __uint_as_float(tb << 16) * ct0 + __uint_as_float(tb & 0xffff0000u) * ct1;
    }
    acc0 = wsum64(acc0);
    acc1 = wsum64(acc1);
    if (l == 0) {
      if (oka) { float lg = acc0 + ob[va]; logitsL[r] = lg; ws[OFF_LOGITS + va] = lg; }
      else logitsL[r] = -1e30f;
      if (r + 1 < r1) {
        if (okb) { float lg = acc1 + ob[vb]; logitsL[r + 1] = lg; ws[OFF_LOGITS + vb] = lg; }
        else logitsL[r + 1] = -1e30f;
      }
    }
  }
  __syncthreads();
  bool valid = (tid < VPB) && (logitsL[tid < VPB ? tid : 0] > -1e29f) && (tid < VPB);
  float m = -1e30f, s = 0.f;
  if (tid < VPB) {
    float lv = logitsL[tid];
    if (lv > -1e29f) { m = lv; s = 1.f; }
  }
  (void)valid;
  rm[tid] = m; rs[tid] = s;
  __syncthreads();
  for (int off = 128; off > 0; off >>= 1) {
    if (tid < off) {
      float m1 = rm[tid], m2 = rm[tid + off];
      float mm = fmaxf(m1, m2);
      rs[tid] = rs[tid] * expf(m1 - mm) + rs[tid + off] * expf(m2 - mm);
      rm[tid] = mm;
    }
    __syncthreads();
  }
  if (tid == 0) { ws[OFF_BM + bid] = rm[0]; ws[OFF_BS + bid] = rs[0]; }
}

// ---------------- D5: global softmax combine + final write + scatter + argmax partial ----------------
__global__ __launch_bounds__(128) void k_d5_final(float* __restrict__ ws, float* __restrict__ out, int t) {
  __shared__ float rm[128], rs[128];
  __shared__ float rv[128];
  __shared__ int ri[128];
  const int tid = threadIdx.x, bid = blockIdx.x;
  float m = -1e30f, s = 0.f;
#pragma unroll
  for (int k = 0; k < 4; ++k) {
    float m2 = ws[OFF_BM + tid * 4 + k], s2 = ws[OFF_BS + tid * 4 + k];
    float mm = fmaxf(m, m2);
    s = s * expf(m - mm) + s2 * expf(m2 - mm);
    m = mm;
  }
  rm[tid] = m; rs[tid] = s;
  __syncthreads();
  for (int off = 64; off > 0; off >>= 1) {
    if (tid < off) {
      float m1 = rm[tid], m2 = rm[tid + off];
      float mm = fmaxf(m1, m2);
      rs[tid] = rs[tid] * expf(m1 - mm) + rs[tid + off] * expf(m2 - mm);
      rm[tid] = mm;
    }
    __syncthreads();
  }
  float M = rm[0], Sg = rs[0];
  float pc = ws[OFF_SCAL];
  float scale = (1.f - pc) / Sg;
  const int* BST = (const int*)(ws + OFF_BSTART);
  const int* SK = (const int*)(ws + OFF_SKEY);
  const int* SP = (const int*)(ws + OFF_SPOS);
  int v = bid * VPB + tid;
  bool act = (tid < VPB) && (v < VTOT);
  float val = -1e30f;
  if (act) {
    val = (v < VOCAB) ? scale * expf(ws[OFF_LOGITS + v] - M) : 0.f;
    int jb = BST[bid], je = BST[bid + 1];
    for (int j = jb; j < je; ++j)
      if (SK[j] == v) val += pc * ws[OFF_ATTN + SP[j]];
    out[(size_t)t * VTOT + v] = val;
  }
  rv[tid] = act ? val : -1e30f; ri[tid] = v;
  __syncthreads();
  for (int off = 64; off > 0; off >>= 1) {
    if (tid < off) {
      float v2 = rv[tid + off]; int i2 = ri[tid + off];
      if (v2 > rv[tid] || (v2 == rv[tid] && i2 < ri[tid])) { rv[tid] = v2; ri[tid] = i2; }
    }
    __syncthreads();
  }
  if (tid == 0) { ws[OFF_AVAL + bid] = rv[0]; ((int*)(ws + OFF_AIDX))[bid] = ri[0]; }
}

// ---------------- host ----------------
extern "C" void kernel_launch(void* const* d_in, const int* in_sizes, int n_in,
                              void* d_out, int out_size, void* d_ws, size_t ws_size,
                              hipStream_t stream) {
  const int*   ids  = (const int*)d_in[0];
  const float* embt = (const float*)d_in[1];
  const float* ewf  = (const float*)d_in[2];
  const float* ehf  = (const float*)d_in[3];
  const float* ebif = (const float*)d_in[4];
  const float* ebhf = (const float*)d_in[5];
  const float* ewb  = (const float*)d_in[6];
  const float* ehb  = (const float*)d_in[7];
  const float* ebib = (const float*)d_in[8];
  const float* ebhb = (const float*)d_in[9];
  const float* dwih = (const float*)d_in[10];
  const float* dwhh = (const float*)d_in[11];
  const float* dbih = (const float*)d_in[12];
  const float* dbhh = (const float*)d_in[13];
  const float* eap  = (const float*)d_in[14];
  const float* dap  = (const float*)d_in[15];
  const float* vp   = (const float*)d_in[16];
  const float* ob   = (const float*)d_in[17];
  const float* sw   = (const float*)d_in[18];
  const float* sb   = (const float*)d_in[19];
  float* out = (float*)d_out;
  float* ws  = (float*)d_ws;

  k_setup<<<1558, 256, 0, stream>>>(ws, ids, embt, ewf, ewb, eap);
  k_xg<<<5120, 256, 0, stream>>>(ws, ebif, ebhf, ebib, ebhb);
  k_outproj<<<dim3(786, 15), 256, 0, stream>>>(embt, vp, ws);
  k_encoder<<<2, 512, 0, stream>>>(ws, ehf, ehb);
  k_encproj<<<1280, 256, 0, stream>>>(ws);
  k_sort<<<1, 512, 0, stream>>>(ws, ids);

  for (int t = 0; t < TDEC; ++t) {
    k_d1_gates<<<20, 256, 0, stream>>>(ws, embt, dwih, dwhh, dbih, dbhh, t);
    k_d2_hs<<<40, 512, 0, stream>>>(ws, dap, t);
    k_d3_attn<<<17, 512, 0, stream>>>(ws, t);
    k_d4_logits<<<512, 256, 0, stream>>>(ws, ob, sw, sb);
    k_d5_final<<<512, 128, 0, stream>>>(ws, out, t);
  }
}